// Round 15
// baseline (549.488 us; speedup 1.0000x reference)
//
#include <hip/hip_runtime.h>
#include <hip/hip_bf16.h>
#include <hip/hip_fp16.h>

typedef _Float16 half8 __attribute__((ext_vector_type(8)));
typedef _Float16 half4 __attribute__((ext_vector_type(4)));
typedef _Float16 h2    __attribute__((ext_vector_type(2)));
typedef float floatx4 __attribute__((ext_vector_type(4)));

__device__ __forceinline__ _Float16 f2h(float f) { return (_Float16)f; }

// eData slot (16B): {src | gt<<24, dst, w01 (2xf16), w2_one (2xf16)}
// dummy slot: {N | NGT<<24, N, 0, 0}
// groups are 8 edges (pad-to-8 per dst)

// ---------------------------------------------------------------------------
__global__ void fill_dummy_kernel(int4* __restrict__ eData, int cap, int N, int NGT)
{
    int i = blockIdx.x * 256 + threadIdx.x;
    if (i < cap) { int4 v = {N | (NGT << 24), N, 0, 0}; eData[i] = v; }
}

__global__ void hist_kernel(const int* __restrict__ dst, int* __restrict__ cnt, int E)
{
    int e = blockIdx.x * 256 + threadIdx.x;
    if (e < E) atomicAdd(&cnt[dst[e]], 1);
}

// exclusive scan of per-node counts PADDED to multiple of 8 -> offP
__global__ void scan1p_kernel(const int* __restrict__ cnt, int* __restrict__ offP,
                              int n, int* __restrict__ blockSums)
{
    __shared__ int sm[256];
    const int t = threadIdx.x;
    const int base = blockIdx.x * 1024 + t * 4;
    int v[4]; int s = 0;
#pragma unroll
    for (int i = 0; i < 4; ++i) {
        v[i] = (base + i < n) ? ((cnt[base + i] + 7) & ~7) : 0;
        s += v[i];
    }
    sm[t] = s; __syncthreads();
#pragma unroll
    for (int off = 1; off < 256; off <<= 1) {
        int y = (t >= off) ? sm[t - off] : 0;
        __syncthreads();
        if (t >= off) sm[t] += y;
        __syncthreads();
    }
    int excl = sm[t] - s;
    if (t == 255) blockSums[blockIdx.x] = sm[255];
    int run = excl;
#pragma unroll
    for (int i = 0; i < 4; ++i) {
        if (base + i < n) offP[base + i] = run;
        run += v[i];
    }
}

__global__ void scan2_kernel(int* __restrict__ blockSums, int nb)
{
    __shared__ int sm[256];
    const int t = threadIdx.x;
    int s = (t < nb) ? blockSums[t] : 0;
    sm[t] = s; __syncthreads();
#pragma unroll
    for (int off = 1; off < 256; off <<= 1) {
        int y = (t >= off) ? sm[t - off] : 0;
        __syncthreads();
        if (t >= off) sm[t] += y;
        __syncthreads();
    }
    if (t < nb) blockSums[t] = sm[t] - s;
}

__global__ void scan3_kernel(int* __restrict__ offP, int n, const int* __restrict__ blockSums)
{
    const int base = blockIdx.x * 1024 + threadIdx.x * 4;
    const int add = blockSums[blockIdx.x];
#pragma unroll
    for (int i = 0; i < 4; ++i)
        if (base + i < n) offP[base + i] += add;
}

// single 16B store per edge into the sorted slot
__global__ void scatter_kernel(const int* __restrict__ src, const int* __restrict__ dst,
                               const float* __restrict__ w, const int* __restrict__ gt,
                               const int* __restrict__ offP, int* __restrict__ cur,
                               int4* __restrict__ eData, int E)
{
    int e = blockIdx.x * 256 + threadIdx.x;
    if (e >= E) return;
    int d = dst[e];
    int p = offP[d] + atomicAdd(&cur[d], 1);
    int s = src[e];
    h2 w01 = { f2h(w[(size_t)e * 3 + 0]), f2h(w[(size_t)e * 3 + 1]) };
    h2 w2o = { f2h(w[(size_t)e * 3 + 2]), (_Float16)1.0f };
    int4 v = { s | (gt[s] << 24), d,
               __builtin_bit_cast(int, w01), __builtin_bit_cast(int, w2o) };
    eData[p] = v;
}

// per-group info: dst (plain) or 0xFFFFFFFF for dummy (8-edge groups)
__global__ void ginfo_kernel(const int4* __restrict__ eData, unsigned* __restrict__ gInfo,
                             int nGroups, int N)
{
    int g = blockIdx.x * 256 + threadIdx.x;
    if (g >= nGroups) return;
    int d = ((const int*)eData)[32 * g + 1];
    gInfo[g] = (d >= N) ? 0xFFFFFFFFu : (unsigned)d;
}

// list of deg-0 nodes (rows never written by edgeW -> need one-time zero)
__global__ void zlist_kernel(const int* __restrict__ cnt, int* __restrict__ zCnt,
                             int* __restrict__ zList, int N)
{
    int d = blockIdx.x * 256 + threadIdx.x;
    if (d < N && cnt[d] == 0) zList[atomicAdd(zCnt, 1)] = d;
}

__global__ void zero_rows_kernel(const int* __restrict__ zList, const int* __restrict__ zCnt,
                                 _Float16* __restrict__ hN)
{
    const int n = *zCnt * 16;                // 16 x 16B chunks per 256B row
    for (int i = blockIdx.x * 256 + threadIdx.x; i < n; i += gridDim.x * 256) {
        const int row = zList[i >> 4], c = (i & 15) * 8;
        int4 zz = {0, 0, 0, 0};
        *(int4*)(hN + (size_t)row * 128 + c) = zz;
    }
}

// ---------------------------------------------------------------------------
// weight prep: W [K,128] fp32 -> out [128,KP] f16 (outcol-major, k minor)
// ---------------------------------------------------------------------------
__global__ void wprep_kernel(const float* __restrict__ W, _Float16* __restrict__ out,
                             int K, int KP)
{
    int idx = blockIdx.x * 256 + threadIdx.x;
    if (idx >= 128 * KP) return;
    int f = idx / KP, k = idx % KP;
    float v = (k < K) ? W[(size_t)k * 128 + f] : 0.0f;
    out[idx] = f2h(v);
}

// w-rows of W1 -> f16 [3][128]
__global__ void wwprep_kernel(const float* __restrict__ W1, int rowOff,
                              _Float16* __restrict__ out)
{
    int idx = blockIdx.x * 256 + threadIdx.x;
    if (idx < 3 * 128) out[idx] = f2h(W1[(size_t)(rowOff + idx / 128) * 128 + (idx & 127)]);
}

// embW1b[g][f] = b1_0[f] + emb[g]@W1_0[:64] (f16); row NGT = zeros (pads)
__global__ void embW1_kernel(const float* __restrict__ emb, const float* __restrict__ W1,
                             const float* __restrict__ b1, _Float16* __restrict__ out, int NGT)
{
    int idx = blockIdx.x * 256 + threadIdx.x;
    if (idx >= (NGT + 1) * 128) return;
    int g = idx >> 7, f = idx & 127;
    float s = 0.0f;
    if (g < NGT) {
        s = b1[f];
        for (int k = 0; k < 64; ++k) s += emb[g * 64 + k] * W1[(size_t)k * 128 + f];
    }
    out[idx] = f2h(s);
}

__global__ void embW2_kernel(const float* __restrict__ emb, const float* __restrict__ W2,
                             float* __restrict__ out, int NGT)
{
    int idx = blockIdx.x * 256 + threadIdx.x;
    if (idx >= NGT * 128) return;
    int g = idx >> 7, f = idx & 127;
    float s = 0.0f;
    for (int k = 0; k < 64; ++k) s += emb[g * 64 + k] * W2[(size_t)k * 128 + f];
    out[idx] = s;
}

// ---------------------------------------------------------------------------
// hW1b = h @ W1[:128] + b1  (dense, per-node; feeds the edge kernel)
// ---------------------------------------------------------------------------
__global__ void __launch_bounds__(512, 2)
hw1_kernel(const _Float16* __restrict__ hA,   // [N,128]
           const _Float16* __restrict__ WT,   // [128 outcol, 128 k] f16
           const float* __restrict__ b1,
           _Float16* __restrict__ out,        // [(N+1),128]
           int N, int tilesPerWave, int nTiles)
{
    __shared__ __align__(16) _Float16 lds[128 * 128];
    const int tid = threadIdx.x;
    for (int s = tid; s < 128 * 16; s += 512) {
        const int row = s / 16, seg = s % 16;
        half8 v = *(const half8*)(WT + (size_t)row * 128 + seg * 8);
        *(half8*)(&lds[row * 128 + ((seg ^ (row & 7)) * 8)]) = v;
    }
    __syncthreads();

    const int lane = tid & 63;
    const int wv   = tid >> 6;
    const int lRow = lane & 15;
    const int lGrp = lane >> 4;

    float b1v[8];
#pragma unroll
    for (int jt = 0; jt < 8; ++jt) b1v[jt] = b1[jt * 16 + lRow];

    const int wave = blockIdx.x * 8 + wv;
    const int t0 = wave * tilesPerWave;
    const int t1 = min(t0 + tilesPerWave, nTiles);

    for (int tile = t0; tile < t1; ++tile) {
        const int i0 = tile * 16;
        const int iA = min(i0 + lRow, N - 1);
        half8 a[4];
#pragma unroll
        for (int kc = 0; kc < 4; ++kc)
            a[kc] = *(const half8*)(hA + (size_t)iA * 128 + kc * 32 + lGrp * 8);

        floatx4 acc[8] = {};
#pragma unroll
        for (int jt = 0; jt < 8; ++jt) {
            const int row = jt * 16 + lRow;
            const int sw = row & 7;
#pragma unroll
            for (int kc = 0; kc < 4; ++kc) {
                half8 b = *(const half8*)(&lds[row * 128 + (((kc * 4 + lGrp) ^ sw) * 8)]);
                acc[jt] = __builtin_amdgcn_mfma_f32_16x16x32_f16(a[kc], b, acc[jt], 0, 0, 0);
            }
        }
#pragma unroll
        for (int r = 0; r < 4; ++r) {
            const int i = i0 + lGrp * 4 + r;
            if (i < N) {
#pragma unroll
                for (int jt = 0; jt < 8; ++jt)
                    out[(size_t)i * 128 + jt * 16 + lRow] = f2h(acc[jt][r] + b1v[jt]);
            }
        }
    }
}

// ---------------------------------------------------------------------------
// edge kernel (ALL layers, no MFMA, packed f16, 8-edge groups, stores only):
//   per lane: 4 independent eData loads -> 4 independent T-gathers -> math.
//   dst-ownership as before (prefix skip + same-dst extension).
// ---------------------------------------------------------------------------
template<bool L0, bool H16>
__global__ void __launch_bounds__(256, 4)
edgeW_kernel(const _Float16* __restrict__ T,    // embW1b (L0) or hW1b
             const _Float16* __restrict__ Wwh,  // [3][128] f16
             const int4* __restrict__ eData,
             const unsigned* __restrict__ gInfo,
             void* __restrict__ hNv, int groupsPerWave, int nGroups)
{
    const int tid  = threadIdx.x;
    const int lane = tid & 63;
    const int wv   = tid >> 6;
    const int sub  = lane >> 5;          // 0/1: edge within pair
    const int col4 = (lane & 31) * 4;    // 4 consecutive output cols

    const h2 z = {(_Float16)0.0f, (_Float16)0.0f};
    const h2 w0a = *(const h2*)(Wwh + 0 * 128 + col4);
    const h2 w0b = *(const h2*)(Wwh + 0 * 128 + col4 + 2);
    const h2 w1a = *(const h2*)(Wwh + 1 * 128 + col4);
    const h2 w1b = *(const h2*)(Wwh + 1 * 128 + col4 + 2);
    const h2 w2a = *(const h2*)(Wwh + 2 * 128 + col4);
    const h2 w2b = *(const h2*)(Wwh + 2 * 128 + col4 + 2);

    const int wave = blockIdx.x * 4 + wv;
    const int g0 = wave * groupsPerWave;
    if (g0 >= nGroups) return;
    const int g1 = min(g0 + groupsPerWave, nGroups);

    int g = g0;
    {
        unsigned gi0 = gInfo[g0];
        if (gi0 == 0xFFFFFFFFu) return;          // dummy suffix starts before us
        if (g0 > 0 && gInfo[g0 - 1] == gi0) {
            // predecessor owns this dst; skip its remaining groups
            do { ++g; } while (g < nGroups && gInfo[g] == gi0);
        }
    }

    int runD = -1;
    h2 a0 = z, a1 = z;

    auto flush = [&]() {
        if (runD < 0) return;
        h2 s0 = a0, s1 = a1;
        int o0 = __shfl_xor(__builtin_bit_cast(int, s0), 32);
        int o1 = __shfl_xor(__builtin_bit_cast(int, s1), 32);
        s0 = s0 + __builtin_bit_cast(h2, o0);
        s1 = s1 + __builtin_bit_cast(h2, o1);
        if (lane < 32) {
            if (H16) {
                int2 pk = { __builtin_bit_cast(int, s0), __builtin_bit_cast(int, s1) };
                *(int2*)((__half*)hNv + (size_t)runD * 128 + col4) = pk;
            } else {
                floatx4 p = {(float)s0[0], (float)s0[1], (float)s1[0], (float)s1[1]};
                *(floatx4*)((float*)hNv + (size_t)runD * 128 + col4) = p;
            }
        }
    };

    while (g < nGroups) {
        const unsigned gi = gInfo[g];
        if (gi == 0xFFFFFFFFu) break;            // dummy tail
        const int dG = (int)gi;
        if (g >= g1 && dG != runD) break;        // extension only while same dst

        const int eb = g * 8;
        // 4 independent eData loads
        const int4 e0 = eData[eb + sub];
        const int4 e1 = eData[eb + 2 + sub];
        const int4 e2 = eData[eb + 4 + sub];
        const int4 e3 = eData[eb + 6 + sub];
        const int r0i = L0 ? (e0.x >> 24) : (e0.x & 0xFFFFFF);
        const int r1i = L0 ? (e1.x >> 24) : (e1.x & 0xFFFFFF);
        const int r2i = L0 ? (e2.x >> 24) : (e2.x & 0xFFFFFF);
        const int r3i = L0 ? (e3.x >> 24) : (e3.x & 0xFFFFFF);
        // 4 independent T-gathers (pads hit the cached zero row)
        const half4 T0 = *(const half4*)(T + (size_t)r0i * 128 + col4);
        const half4 T1 = *(const half4*)(T + (size_t)r1i * 128 + col4);
        const half4 T2 = *(const half4*)(T + (size_t)r2i * 128 + col4);
        const half4 T3 = *(const half4*)(T + (size_t)r3i * 128 + col4);

        const h2 wA0 = __builtin_bit_cast(h2, e0.z), wA2 = __builtin_bit_cast(h2, e0.w);
        const h2 wB0 = __builtin_bit_cast(h2, e1.z), wB2 = __builtin_bit_cast(h2, e1.w);
        const h2 wC0 = __builtin_bit_cast(h2, e2.z), wC2 = __builtin_bit_cast(h2, e2.w);
        const h2 wD0 = __builtin_bit_cast(h2, e3.z), wD2 = __builtin_bit_cast(h2, e3.w);

        h2 mA0 = h2{T0[0], T0[1]} + wA0[0] * w0a + wA0[1] * w1a + wA2[0] * w2a;
        h2 mA1 = h2{T0[2], T0[3]} + wA0[0] * w0b + wA0[1] * w1b + wA2[0] * w2b;
        h2 mB0 = h2{T1[0], T1[1]} + wB0[0] * w0a + wB0[1] * w1a + wB2[0] * w2a;
        h2 mB1 = h2{T1[2], T1[3]} + wB0[0] * w0b + wB0[1] * w1b + wB2[0] * w2b;
        h2 mC0 = h2{T2[0], T2[1]} + wC0[0] * w0a + wC0[1] * w1a + wC2[0] * w2a;
        h2 mC1 = h2{T2[2], T2[3]} + wC0[0] * w0b + wC0[1] * w1b + wC2[0] * w2b;
        h2 mD0 = h2{T3[0], T3[1]} + wD0[0] * w0a + wD0[1] * w1a + wD2[0] * w2a;
        h2 mD1 = h2{T3[2], T3[3]} + wD0[0] * w0b + wD0[1] * w1b + wD2[0] * w2b;

        h2 r0 = (__builtin_elementwise_max(mA0, z) + __builtin_elementwise_max(mB0, z))
              + (__builtin_elementwise_max(mC0, z) + __builtin_elementwise_max(mD0, z));
        h2 r1 = (__builtin_elementwise_max(mA1, z) + __builtin_elementwise_max(mB1, z))
              + (__builtin_elementwise_max(mC1, z) + __builtin_elementwise_max(mD1, z));

        if (dG == runD) {
            a0 = a0 + r0; a1 = a1 + r1;
        } else {
            flush();
            runD = dG;
            a0 = r0; a1 = r1;
        }
        ++g;
    }
    flush();
}

// ---------------------------------------------------------------------------
// node kernel (2-tile batched, 512 threads -> 16 waves/CU)
// ---------------------------------------------------------------------------
template<bool H16, bool L0, bool LAST>
__global__ void __launch_bounds__(512, 2)
node_kernel(const _Float16* __restrict__ hA,    // [N,128] (unused if L0)
            const void* __restrict__ hNv,       // [N,128] f16 or f32
            const _Float16* __restrict__ W2T,   // [128,K2]
            const float* __restrict__ embW2,    // [30,128] (L0 only)
            const int* __restrict__ gt,         // (L0 only)
            const int* __restrict__ n2g,
            _Float16* __restrict__ hOut,        // if !LAST
            float* __restrict__ fOut,           // if LAST
            float* __restrict__ readout,
            int N, int tilesPerWave, int nTiles, int layerOff)
{
    constexpr int K2  = L0 ? 128 : 256;
    constexpr int KCA = L0 ? 0 : 4;
    constexpr int KC  = K2 / 32;
    constexpr int SPR = K2 / 8;
    __shared__ __align__(16) _Float16 lds[128 * K2];

    const int tid = threadIdx.x;
    for (int s = tid; s < 128 * SPR; s += 512) {
        const int row = s / SPR, seg = s % SPR;
        half8 v = *(const half8*)(W2T + (size_t)row * K2 + seg * 8);
        *(half8*)(&lds[row * K2 + ((seg ^ (row & 7)) * 8)]) = v;
    }
    __syncthreads();

    const int lane = tid & 63;
    const int wv   = tid >> 6;
    const int lRow = lane & 15;
    const int lGrp = lane >> 4;
    const int wave = blockIdx.x * 8 + wv;
    const int t0 = wave * tilesPerWave;
    const int t1 = min(t0 + tilesPerWave, nTiles);
    if (t0 >= t1) return;

    int gCur = -1; float racc[8];
#pragma unroll
    for (int jt = 0; jt < 8; ++jt) racc[jt] = 0.0f;

    auto loadA = [&](int i0, half8 (&afrag)[KC]) {
        const int iA = min(i0 + lRow, N - 1);
#pragma unroll
        for (int kc = 0; kc < KCA; ++kc)
            afrag[kc] = *(const half8*)(hA + (size_t)iA * 128 + kc * 32 + lGrp * 8);
        if (H16) {
            const _Float16* hN = (const _Float16*)hNv;
#pragma unroll
            for (int kc = KCA; kc < KC; ++kc)
                afrag[kc] = *(const half8*)(hN + (size_t)iA * 128 + (kc - KCA) * 32 + lGrp * 8);
        } else {
            const float* hN = (const float*)hNv;
#pragma unroll
            for (int kc = KCA; kc < KC; ++kc) {
                const float* p = hN + (size_t)iA * 128 + (kc - KCA) * 32 + lGrp * 8;
                floatx4 f0 = *(const floatx4*)(p);
                floatx4 f1 = *(const floatx4*)(p + 4);
                half8 a;
#pragma unroll
                for (int i = 0; i < 4; ++i) { a[i] = f2h(f0[i]); a[i + 4] = f2h(f1[i]); }
                afrag[kc] = a;
            }
        }
    };

    auto epilogue = [&](int i0, floatx4 (&acc)[8]) {
        if (L0) {
#pragma unroll
            for (int r = 0; r < 4; ++r) {
                const int i = min(i0 + lGrp * 4 + r, N - 1);
                const int g_t = gt[i];
#pragma unroll
                for (int jt = 0; jt < 8; ++jt)
                    acc[jt][r] += embW2[(size_t)g_t * 128 + jt * 16 + lRow];
            }
        }
        float scl[4];
#pragma unroll
        for (int r = 0; r < 4; ++r) {
            float s = 0.f;
#pragma unroll
            for (int jt = 0; jt < 8; ++jt) {
                float v = fmaxf(acc[jt][r], 0.0f);
                s += v * v;
            }
#pragma unroll
            for (int m = 1; m <= 8; m <<= 1) s += __shfl_xor(s, m);
            scl[r] = 1.0f / fmaxf(sqrtf(s), 1e-12f);
        }
#pragma unroll
        for (int r = 0; r < 4; ++r) {
            const int i = i0 + lGrp * 4 + r;
            if (i < N) {
#pragma unroll
                for (int jt = 0; jt < 8; ++jt) {
                    float v = fmaxf(acc[jt][r], 0.0f) * scl[r];
                    if (LAST) fOut[(size_t)i * 128 + jt * 16 + lRow] = v;
                    else      hOut[(size_t)i * 128 + jt * 16 + lRow] = f2h(v);
                }
            }
        }
        const int gFirst = n2g[min(i0, N - 1)];
        const int gLast  = n2g[min(i0 + 15, N - 1)];
        if (gFirst == gLast && i0 + 15 < N) {
            if (gFirst != gCur) {
                if (gCur >= 0 && lane < 16) {
#pragma unroll
                    for (int jt = 0; jt < 8; ++jt)
                        unsafeAtomicAdd(&readout[(size_t)gCur * 384 + layerOff + jt * 16 + lane], racc[jt]);
                }
                gCur = gFirst;
#pragma unroll
                for (int jt = 0; jt < 8; ++jt) racc[jt] = 0.0f;
            }
#pragma unroll
            for (int jt = 0; jt < 8; ++jt) {
                float t = 0.f;
#pragma unroll
                for (int r = 0; r < 4; ++r) t += fmaxf(acc[jt][r], 0.0f) * scl[r];
                t += __shfl_xor(t, 16);
                t += __shfl_xor(t, 32);
                racc[jt] += t;
            }
        } else {
            if (gCur >= 0 && lane < 16) {
#pragma unroll
                for (int jt = 0; jt < 8; ++jt)
                    unsafeAtomicAdd(&readout[(size_t)gCur * 384 + layerOff + jt * 16 + lane], racc[jt]);
            }
            gCur = -1;
#pragma unroll
            for (int jt = 0; jt < 8; ++jt) racc[jt] = 0.0f;
#pragma unroll
            for (int r = 0; r < 4; ++r) {
                const int i = i0 + lGrp * 4 + r;
                if (i < N) {
                    const int g = n2g[i];
#pragma unroll
                    for (int jt = 0; jt < 8; ++jt) {
                        float v = fmaxf(acc[jt][r], 0.0f) * scl[r];
                        unsafeAtomicAdd(&readout[(size_t)g * 384 + layerOff + jt * 16 + lRow], v);
                    }
                }
            }
        }
    };

    for (int tile = t0; tile < t1; tile += 2) {
        const bool has2 = (tile + 1 < t1);
        const int i0a = tile * 16;
        const int i0b = has2 ? (tile + 1) * 16 : i0a;

        half8 afA[KC], afB[KC];
        loadA(i0a, afA);
        loadA(i0b, afB);

        floatx4 accA[8] = {}, accB[8] = {};
#pragma unroll
        for (int jt = 0; jt < 8; ++jt) {
            const int rb = (jt * 16 + lRow) * K2;
            const int sw = (jt * 16 + lRow) & 7;
#pragma unroll
            for (int kc = 0; kc < KC; ++kc) {
                half8 b = *(const half8*)(&lds[rb + (((kc * 4 + lGrp) ^ sw) * 8)]);
                accA[jt] = __builtin_amdgcn_mfma_f32_16x16x32_f16(afA[kc], b, accA[jt], 0, 0, 0);
                accB[jt] = __builtin_amdgcn_mfma_f32_16x16x32_f16(afB[kc], b, accB[jt], 0, 0, 0);
            }
        }
        epilogue(i0a, accA);
        if (has2) epilogue(i0b, accB);
    }
    if (gCur >= 0 && lane < 16) {
#pragma unroll
        for (int jt = 0; jt < 8; ++jt)
            unsafeAtomicAdd(&readout[(size_t)gCur * 384 + layerOff + jt * 16 + lane], racc[jt]);
    }
}

// ---------------------------------------------------------------------------
extern "C" void kernel_launch(void* const* d_in, const int* in_sizes, int n_in,
                              void* d_out, int out_size, void* d_ws, size_t ws_size,
                              hipStream_t stream)
{
    const int*   gate_type = (const int*)d_in[0];
    const int*   src  = (const int*)d_in[1];
    const int*   dst  = (const int*)d_in[2];
    const float* wE   = (const float*)d_in[3];
    const int*   n2g  = (const int*)d_in[4];
    const float* emb  = (const float*)d_in[5];
    const float* W1_0 = (const float*)d_in[6];
    const float* b1_0 = (const float*)d_in[7];
    const float* W2_0 = (const float*)d_in[8];
    const float* W1_1 = (const float*)d_in[9];
    const float* b1_1 = (const float*)d_in[10];
    const float* W2_1 = (const float*)d_in[11];
    const float* W1_2 = (const float*)d_in[12];
    const float* b1_2 = (const float*)d_in[13];
    const float* W2_2 = (const float*)d_in[14];

    const int N = in_sizes[0];
    const int E = in_sizes[1];
    const int NGT = in_sizes[5] / 64;
    const int cap = (E + 7 * N + 63) & ~63;       // pad-to-8 capacity

    char* ws = (char*)d_ws;
    size_t off = 0;
    auto alloc = [&](size_t bytes) { void* p = ws + off; off = (off + bytes + 255) & ~255ULL; return p; };
    _Float16* hBuf  = (_Float16*)alloc((size_t)N * 128 * 2);
    int4*     eData = (int4*)alloc(((size_t)cap + 16) * 16);
    unsigned* gInfo = (unsigned*)alloc(((size_t)cap / 8 + 8) * 4);
    int*      cnt   = (int*)alloc((size_t)N * 4);
    int*      offP  = (int*)alloc((size_t)N * 4);
    int*      cur   = (int*)alloc((size_t)N * 4);
    int*      bSums = (int*)alloc(256 * 4);
    int*      zCnt  = (int*)alloc(256);
    int*      zList = (int*)alloc((size_t)N * 4);
    _Float16* W1T1  = (_Float16*)alloc((size_t)128 * 128 * 2);
    _Float16* W1T2  = (_Float16*)alloc((size_t)128 * 128 * 2);
    _Float16* W2T0  = (_Float16*)alloc((size_t)128 * 128 * 2);
    _Float16* W2T1  = (_Float16*)alloc((size_t)128 * 256 * 2);
    _Float16* W2T2  = (_Float16*)alloc((size_t)128 * 256 * 2);
    _Float16* Wwh0  = (_Float16*)alloc((size_t)3 * 128 * 2);
    _Float16* Wwh1  = (_Float16*)alloc((size_t)3 * 128 * 2);
    _Float16* Wwh2  = (_Float16*)alloc((size_t)3 * 128 * 2);
    _Float16* eW1b  = (_Float16*)alloc((size_t)(NGT + 1) * 128 * 2);
    float*    eW2   = (float*)alloc((size_t)NGT * 128 * 4);
    _Float16* hW1b  = (_Float16*)alloc(((size_t)N + 1) * 128 * 2);
    size_t hn16_off = off;
    const bool h16 = (ws_size >= hn16_off + (size_t)N * 128 * 2 + 256);
    _Float16* hN16 = (_Float16*)alloc((size_t)N * 128 * 2);

    float* readout = (float*)d_out + (size_t)N * 128;  // [G,384]
    void*  hN      = h16 ? (void*)hN16 : (void*)d_out;

    const int nGroups = cap / 8;
    const int nTiles  = (N + 15) / 16;
    const int EB = 2048;                                 // edgeW blocks (4 waves)
    const int gpw = (nGroups + EB * 4 - 1) / (EB * 4);
    const int NB = 256;                                  // node blocks (8 waves)
    const int tpwN = (nTiles + NB * 8 - 1) / (NB * 8);
    const int HB = 256;                                  // hw1 blocks (8 waves)
    const int tpwH = (nTiles + HB * 8 - 1) / (HB * 8);
    const int nb = (N + 1023) / 1024;

    // ---- init + counting sort (padded to 8 per dst, 16B/slot payload) ----
    hipMemsetAsync(cnt, 0, (size_t)N * 4, stream);
    hipMemsetAsync(cur, 0, (size_t)N * 4, stream);
    hipMemsetAsync(zCnt, 0, 4, stream);
    hipMemsetAsync(hW1b + (size_t)N * 128, 0, 256, stream);   // zero pad row
    fill_dummy_kernel<<<(cap + 16 + 255) / 256, 256, 0, stream>>>(eData, cap + 16, N, NGT);
    hist_kernel<<<(E + 255) / 256, 256, 0, stream>>>(dst, cnt, E);
    scan1p_kernel<<<nb, 256, 0, stream>>>(cnt, offP, N, bSums);
    scan2_kernel<<<1, 256, 0, stream>>>(bSums, nb);
    scan3_kernel<<<nb, 256, 0, stream>>>(offP, N, bSums);
    scatter_kernel<<<(E + 255) / 256, 256, 0, stream>>>(src, dst, wE, gate_type,
                                                        offP, cur, eData, E);
    ginfo_kernel<<<(nGroups + 255) / 256, 256, 0, stream>>>(eData, gInfo, nGroups, N);
    zlist_kernel<<<(N + 255) / 256, 256, 0, stream>>>(cnt, zCnt, zList, N);

    // ---- weight prep ----
    embW1_kernel<<<((NGT + 1) * 128 + 255) / 256, 256, 0, stream>>>(emb, W1_0, b1_0, eW1b, NGT);
    embW2_kernel<<<(NGT * 128 + 255) / 256, 256, 0, stream>>>(emb, W2_0, eW2, NGT);
    wprep_kernel<<<(128 * 128 + 255) / 256, 256, 0, stream>>>(W1_1, W1T1, 128, 128);
    wprep_kernel<<<(128 * 128 + 255) / 256, 256, 0, stream>>>(W1_2, W1T2, 128, 128);
    wprep_kernel<<<(128 * 128 + 255) / 256, 256, 0, stream>>>(W2_0 + (size_t)64 * 128, W2T0, 128, 128);
    wprep_kernel<<<(128 * 256 + 255) / 256, 256, 0, stream>>>(W2_1, W2T1, 256, 256);
    wprep_kernel<<<(128 * 256 + 255) / 256, 256, 0, stream>>>(W2_2, W2T2, 256, 256);
    wwprep_kernel<<<2, 256, 0, stream>>>(W1_0, 64, Wwh0);
    wwprep_kernel<<<2, 256, 0, stream>>>(W1_1, 128, Wwh1);
    wwprep_kernel<<<2, 256, 0, stream>>>(W1_2, 128, Wwh2);

    if (h16) {
        hipMemsetAsync(readout, 0, (size_t)(out_size - N * 128) * 4, stream);
        zero_rows_kernel<<<128, 256, 0, stream>>>(zList, zCnt, hN16);  // deg-0 rows, once
        // layer 0
        edgeW_kernel<true, true><<<EB, 256, 0, stream>>>(eW1b, Wwh0, eData, gInfo, hN, gpw, nGroups);
        node_kernel<true, true, false><<<NB, 512, 0, stream>>>(nullptr, hN, W2T0, eW2, gate_type, n2g,
                                                               hBuf, nullptr, readout, N, tpwN, nTiles, 0);
        // layer 1
        hw1_kernel<<<HB, 512, 0, stream>>>(hBuf, W1T1, b1_1, hW1b, N, tpwH, nTiles);
        edgeW_kernel<false, true><<<EB, 256, 0, stream>>>(hW1b, Wwh1, eData, gInfo, hN, gpw, nGroups);
        node_kernel<true, false, false><<<NB, 512, 0, stream>>>(hBuf, hN, W2T1, nullptr, nullptr, n2g,
                                                                hBuf, nullptr, readout, N, tpwN, nTiles, 128);
        // layer 2
        hw1_kernel<<<HB, 512, 0, stream>>>(hBuf, W1T2, b1_2, hW1b, N, tpwH, nTiles);
        edgeW_kernel<false, true><<<EB, 256, 0, stream>>>(hW1b, Wwh2, eData, gInfo, hN, gpw, nGroups);
        node_kernel<true, false, true><<<NB, 512, 0, stream>>>(hBuf, hN, W2T2, nullptr, nullptr, n2g,
                                                               nullptr, (float*)d_out, readout, N, tpwN, nTiles, 256);
    } else {
        hipMemsetAsync(d_out, 0, (size_t)out_size * 4, stream);
        // layer 0
        edgeW_kernel<true, false><<<EB, 256, 0, stream>>>(eW1b, Wwh0, eData, gInfo, hN, gpw, nGroups);
        node_kernel<false, true, false><<<NB, 512, 0, stream>>>(nullptr, hN, W2T0, eW2, gate_type, n2g,
                                                                hBuf, nullptr, readout, N, tpwN, nTiles, 0);
        // layer 1
        hw1_kernel<<<HB, 512, 0, stream>>>(hBuf, W1T1, b1_1, hW1b, N, tpwH, nTiles);
        hipMemsetAsync(d_out, 0, (size_t)N * 128 * 4, stream);
        edgeW_kernel<false, false><<<EB, 256, 0, stream>>>(hW1b, Wwh1, eData, gInfo, hN, gpw, nGroups);
        node_kernel<false, false, false><<<NB, 512, 0, stream>>>(hBuf, hN, W2T1, nullptr, nullptr, n2g,
                                                                 hBuf, nullptr, readout, N, tpwN, nTiles, 128);
        // layer 2
        hw1_kernel<<<HB, 512, 0, stream>>>(hBuf, W1T2, b1_2, hW1b, N, tpwH, nTiles);
        hipMemsetAsync(d_out, 0, (size_t)N * 128 * 4, stream);
        edgeW_kernel<false, false><<<EB, 256, 0, stream>>>(hW1b, Wwh2, eData, gInfo, hN, gpw, nGroups);
        node_kernel<false, false, true><<<NB, 512, 0, stream>>>(hBuf, hN, W2T2, nullptr, nullptr, n2g,
                                                                nullptr, (float*)d_out, readout, N, tpwN, nTiles, 256);
    }
}

// Round 16
// 504.531 us; speedup vs baseline: 1.0891x; 1.0891x over previous
//
#include <hip/hip_runtime.h>
#include <hip/hip_bf16.h>
#include <hip/hip_fp16.h>

typedef _Float16 half8 __attribute__((ext_vector_type(8)));
typedef _Float16 half4 __attribute__((ext_vector_type(4)));
typedef _Float16 h2    __attribute__((ext_vector_type(2)));
typedef float floatx4 __attribute__((ext_vector_type(4)));

__device__ __forceinline__ _Float16 f2h(float f) { return (_Float16)f; }

// eData slot (16B): {src | gt<<24, dst, w01 (2xf16), w2_one (2xf16)}
// dummy slot: {N | NGT<<24, N, 0, 0};  groups are 4 edges (pad-to-4 per dst)

// ---------------------------------------------------------------------------
__global__ void fill_dummy_kernel(int4* __restrict__ eData, int cap, int N, int NGT)
{
    int i = blockIdx.x * 256 + threadIdx.x;
    if (i < cap) { int4 v = {N | (NGT << 24), N, 0, 0}; eData[i] = v; }
}

__global__ void hist_kernel(const int* __restrict__ dst, int* __restrict__ cnt, int E)
{
    int e = blockIdx.x * 256 + threadIdx.x;
    if (e < E) atomicAdd(&cnt[dst[e]], 1);
}

// exclusive scan of per-node counts PADDED to multiple of 4 -> offP
__global__ void scan1p_kernel(const int* __restrict__ cnt, int* __restrict__ offP,
                              int n, int* __restrict__ blockSums)
{
    __shared__ int sm[256];
    const int t = threadIdx.x;
    const int base = blockIdx.x * 1024 + t * 4;
    int v[4]; int s = 0;
#pragma unroll
    for (int i = 0; i < 4; ++i) {
        v[i] = (base + i < n) ? ((cnt[base + i] + 3) & ~3) : 0;
        s += v[i];
    }
    sm[t] = s; __syncthreads();
#pragma unroll
    for (int off = 1; off < 256; off <<= 1) {
        int y = (t >= off) ? sm[t - off] : 0;
        __syncthreads();
        if (t >= off) sm[t] += y;
        __syncthreads();
    }
    int excl = sm[t] - s;
    if (t == 255) blockSums[blockIdx.x] = sm[255];
    int run = excl;
#pragma unroll
    for (int i = 0; i < 4; ++i) {
        if (base + i < n) offP[base + i] = run;
        run += v[i];
    }
}

__global__ void scan2_kernel(int* __restrict__ blockSums, int nb)
{
    __shared__ int sm[256];
    const int t = threadIdx.x;
    int s = (t < nb) ? blockSums[t] : 0;
    sm[t] = s; __syncthreads();
#pragma unroll
    for (int off = 1; off < 256; off <<= 1) {
        int y = (t >= off) ? sm[t - off] : 0;
        __syncthreads();
        if (t >= off) sm[t] += y;
        __syncthreads();
    }
    if (t < nb) blockSums[t] = sm[t] - s;
}

__global__ void scan3_kernel(int* __restrict__ offP, int n, const int* __restrict__ blockSums)
{
    const int base = blockIdx.x * 1024 + threadIdx.x * 4;
    const int add = blockSums[blockIdx.x];
#pragma unroll
    for (int i = 0; i < 4; ++i)
        if (base + i < n) offP[base + i] += add;
}

// single 16B store per edge into the sorted slot
__global__ void scatter_kernel(const int* __restrict__ src, const int* __restrict__ dst,
                               const float* __restrict__ w, const int* __restrict__ gt,
                               const int* __restrict__ offP, int* __restrict__ cur,
                               int4* __restrict__ eData, int E)
{
    int e = blockIdx.x * 256 + threadIdx.x;
    if (e >= E) return;
    int d = dst[e];
    int p = offP[d] + atomicAdd(&cur[d], 1);
    int s = src[e];
    h2 w01 = { f2h(w[(size_t)e * 3 + 0]), f2h(w[(size_t)e * 3 + 1]) };
    h2 w2o = { f2h(w[(size_t)e * 3 + 2]), (_Float16)1.0f };
    int4 v = { s | (gt[s] << 24), d,
               __builtin_bit_cast(int, w01), __builtin_bit_cast(int, w2o) };
    eData[p] = v;
}

// per-group info: dG (24b) | cross-wave flag (bit31); dummy group = 0xFFFFFFFF
__global__ void ginfo_kernel(const int4* __restrict__ eData,
                             const int* __restrict__ cnt, const int* __restrict__ offP,
                             unsigned* __restrict__ gInfo,
                             int nGroups, int N, int gpw)
{
    int g = blockIdx.x * 256 + threadIdx.x;
    if (g >= nGroups) return;
    const int* ei = (const int*)eData;
    int d = ei[16 * g + 1];
    if (d >= N) { gInfo[g] = 0xFFFFFFFFu; return; }
    int cntP = (cnt[d] + 3) & ~3;
    int gA = offP[d] >> 2;
    int gB = gA + (cntP >> 2) - 1;
    bool cross = (gA / gpw) != (gB / gpw);
    gInfo[g] = (unsigned)d | (cross ? 0x80000000u : 0u);
}

// ---------------------------------------------------------------------------
// weight prep: W [K,128] fp32 -> out [128,KP] f16 (outcol-major, k minor)
// ---------------------------------------------------------------------------
__global__ void wprep_kernel(const float* __restrict__ W, _Float16* __restrict__ out,
                             int K, int KP)
{
    int idx = blockIdx.x * 256 + threadIdx.x;
    if (idx >= 128 * KP) return;
    int f = idx / KP, k = idx % KP;
    float v = (k < K) ? W[(size_t)k * 128 + f] : 0.0f;
    out[idx] = f2h(v);
}

// w-rows of W1 -> f16 [3][128]
__global__ void wwprep_kernel(const float* __restrict__ W1, int rowOff,
                              _Float16* __restrict__ out)
{
    int idx = blockIdx.x * 256 + threadIdx.x;
    if (idx < 3 * 128) out[idx] = f2h(W1[(size_t)(rowOff + idx / 128) * 128 + (idx & 127)]);
}

// embW1b[g][f] = b1_0[f] + emb[g]@W1_0[:64] (f16); row NGT = zeros (pads)
__global__ void embW1_kernel(const float* __restrict__ emb, const float* __restrict__ W1,
                             const float* __restrict__ b1, _Float16* __restrict__ out, int NGT)
{
    int idx = blockIdx.x * 256 + threadIdx.x;
    if (idx >= (NGT + 1) * 128) return;
    int g = idx >> 7, f = idx & 127;
    float s = 0.0f;
    if (g < NGT) {
        s = b1[f];
        for (int k = 0; k < 64; ++k) s += emb[g * 64 + k] * W1[(size_t)k * 128 + f];
    }
    out[idx] = f2h(s);
}

__global__ void embW2_kernel(const float* __restrict__ emb, const float* __restrict__ W2,
                             float* __restrict__ out, int NGT)
{
    int idx = blockIdx.x * 256 + threadIdx.x;
    if (idx >= NGT * 128) return;
    int g = idx >> 7, f = idx & 127;
    float s = 0.0f;
    for (int k = 0; k < 64; ++k) s += emb[g * 64 + k] * W2[(size_t)k * 128 + f];
    out[idx] = s;
}

// ---------------------------------------------------------------------------
// hW1b = h @ W1[:128] + b1  (dense, per-node; feeds the edge kernel)
// ---------------------------------------------------------------------------
__global__ void __launch_bounds__(512, 2)
hw1_kernel(const _Float16* __restrict__ hA,   // [N,128]
           const _Float16* __restrict__ WT,   // [128 outcol, 128 k] f16
           const float* __restrict__ b1,
           _Float16* __restrict__ out,        // [(N+1),128]
           int N, int tilesPerWave, int nTiles)
{
    __shared__ __align__(16) _Float16 lds[128 * 128];
    const int tid = threadIdx.x;
    for (int s = tid; s < 128 * 16; s += 512) {
        const int row = s / 16, seg = s % 16;
        half8 v = *(const half8*)(WT + (size_t)row * 128 + seg * 8);
        *(half8*)(&lds[row * 128 + ((seg ^ (row & 7)) * 8)]) = v;
    }
    __syncthreads();

    const int lane = tid & 63;
    const int wv   = tid >> 6;
    const int lRow = lane & 15;
    const int lGrp = lane >> 4;

    float b1v[8];
#pragma unroll
    for (int jt = 0; jt < 8; ++jt) b1v[jt] = b1[jt * 16 + lRow];

    const int wave = blockIdx.x * 8 + wv;
    const int t0 = wave * tilesPerWave;
    const int t1 = min(t0 + tilesPerWave, nTiles);

    for (int tile = t0; tile < t1; ++tile) {
        const int i0 = tile * 16;
        const int iA = min(i0 + lRow, N - 1);
        half8 a[4];
#pragma unroll
        for (int kc = 0; kc < 4; ++kc)
            a[kc] = *(const half8*)(hA + (size_t)iA * 128 + kc * 32 + lGrp * 8);

        floatx4 acc[8] = {};
#pragma unroll
        for (int jt = 0; jt < 8; ++jt) {
            const int row = jt * 16 + lRow;
            const int sw = row & 7;
#pragma unroll
            for (int kc = 0; kc < 4; ++kc) {
                half8 b = *(const half8*)(&lds[row * 128 + (((kc * 4 + lGrp) ^ sw) * 8)]);
                acc[jt] = __builtin_amdgcn_mfma_f32_16x16x32_f16(a[kc], b, acc[jt], 0, 0, 0);
            }
        }
#pragma unroll
        for (int r = 0; r < 4; ++r) {
            const int i = i0 + lGrp * 4 + r;
            if (i < N) {
#pragma unroll
                for (int jt = 0; jt < 8; ++jt)
                    out[(size_t)i * 128 + jt * 16 + lRow] = f2h(acc[jt][r] + b1v[jt]);
            }
        }
    }
}

// ---------------------------------------------------------------------------
// edge kernel: lane = (edge-slot = lane>>4, 8 cols = (lane&15)*8).
// Per 4-edge group: ONE 16B/lane eData load + ONE 16B/lane T row-read.
// Run-merge across same-dst groups; flush = reduce over edge-slots + one
// 16B/lane row store (atomics only for cross-wave dsts, gInfo bit31).
// ---------------------------------------------------------------------------
template<bool L0, bool H16>
__global__ void __launch_bounds__(256, 4)
edgeW_kernel(const _Float16* __restrict__ T,    // embW1b (L0) or hW1b
             const _Float16* __restrict__ Wwh,  // [3][128] f16
             const int4* __restrict__ eData,
             const unsigned* __restrict__ gInfo,
             void* __restrict__ hNv, int groupsPerWave, int nGroups)
{
    const int tid  = threadIdx.x;
    const int lane = tid & 63;
    const int wv   = tid >> 6;
    const int eidx = lane >> 4;          // edge slot 0..3 within group
    const int c8   = (lane & 15) * 8;    // 8 consecutive output cols

    const h2 z = {(_Float16)0.0f, (_Float16)0.0f};
    h2 w0[4], w1[4], w2[4];
#pragma unroll
    for (int j = 0; j < 4; ++j) {
        w0[j] = *(const h2*)(Wwh + 0 * 128 + c8 + 2 * j);
        w1[j] = *(const h2*)(Wwh + 1 * 128 + c8 + 2 * j);
        w2[j] = *(const h2*)(Wwh + 2 * 128 + c8 + 2 * j);
    }

    const int wave = blockIdx.x * 4 + wv;
    const int g0 = wave * groupsPerWave;
    const int g1 = min(g0 + groupsPerWave, nGroups);
    if (g0 >= g1) return;

    int runD = -1; bool runCross = false;
    h2 a0 = z, a1 = z, a2 = z, a3 = z;   // per-lane partials (own edge slot)

    auto flush = [&]() {
        if (runD < 0) return;
        h2 s0 = a0, s1 = a1, s2 = a2, s3 = a3;
        // reduce over the 4 edge-slot groups (xor 16, then 32)
#pragma unroll
        for (int m = 16; m <= 32; m <<= 1) {
            int t0_ = __shfl_xor(__builtin_bit_cast(int, s0), m);
            int t1_ = __shfl_xor(__builtin_bit_cast(int, s1), m);
            int t2_ = __shfl_xor(__builtin_bit_cast(int, s2), m);
            int t3_ = __shfl_xor(__builtin_bit_cast(int, s3), m);
            s0 = s0 + __builtin_bit_cast(h2, t0_);
            s1 = s1 + __builtin_bit_cast(h2, t1_);
            s2 = s2 + __builtin_bit_cast(h2, t2_);
            s3 = s3 + __builtin_bit_cast(h2, t3_);
        }
        if (lane < 16) {
            if (H16) {
                if (runCross) {
                    __half2* p = (__half2*)((__half*)hNv + (size_t)runD * 128 + c8);
                    unsafeAtomicAdd(p + 0, __builtin_bit_cast(__half2, s0));
                    unsafeAtomicAdd(p + 1, __builtin_bit_cast(__half2, s1));
                    unsafeAtomicAdd(p + 2, __builtin_bit_cast(__half2, s2));
                    unsafeAtomicAdd(p + 3, __builtin_bit_cast(__half2, s3));
                } else {
                    int4 pk = { __builtin_bit_cast(int, s0), __builtin_bit_cast(int, s1),
                                __builtin_bit_cast(int, s2), __builtin_bit_cast(int, s3) };
                    *(int4*)((__half*)hNv + (size_t)runD * 128 + c8) = pk;
                }
            } else {
                float f[8] = {(float)s0[0], (float)s0[1], (float)s1[0], (float)s1[1],
                              (float)s2[0], (float)s2[1], (float)s3[0], (float)s3[1]};
                float* p = (float*)hNv + (size_t)runD * 128 + c8;
                if (runCross) {
#pragma unroll
                    for (int j = 0; j < 8; ++j) unsafeAtomicAdd(p + j, f[j]);
                } else {
                    floatx4 q0 = {f[0], f[1], f[2], f[3]};
                    floatx4 q1 = {f[4], f[5], f[6], f[7]};
                    *(floatx4*)(p) = q0;
                    *(floatx4*)(p + 4) = q1;
                }
            }
        }
    };

    for (int g = g0; g < g1; ++g) {
        const unsigned gi = gInfo[g];
        if (gi == 0xFFFFFFFFu) break;    // dummy suffix begins
        const int dG = (int)(gi & 0xFFFFFFu);

        const int4 e = eData[g * 4 + eidx];              // 4 addrs / wave
        const int r_ = L0 ? (e.x >> 24) : (e.x & 0xFFFFFF);
        const half8 Tv = *(const half8*)(T + (size_t)r_ * 128 + c8);  // 4 rows / wave
        const h2 w01 = __builtin_bit_cast(h2, e.z);
        const h2 w2o = __builtin_bit_cast(h2, e.w);

        h2 m0 = h2{Tv[0], Tv[1]} + w01[0] * w0[0] + w01[1] * w1[0] + w2o[0] * w2[0];
        h2 m1 = h2{Tv[2], Tv[3]} + w01[0] * w0[1] + w01[1] * w1[1] + w2o[0] * w2[1];
        h2 m2 = h2{Tv[4], Tv[5]} + w01[0] * w0[2] + w01[1] * w1[2] + w2o[0] * w2[2];
        h2 m3 = h2{Tv[6], Tv[7]} + w01[0] * w0[3] + w01[1] * w1[3] + w2o[0] * w2[3];
        h2 r0 = __builtin_elementwise_max(m0, z);
        h2 r1 = __builtin_elementwise_max(m1, z);
        h2 r2 = __builtin_elementwise_max(m2, z);
        h2 r3 = __builtin_elementwise_max(m3, z);

        if (dG == runD) {
            a0 = a0 + r0; a1 = a1 + r1; a2 = a2 + r2; a3 = a3 + r3;
        } else {
            flush();
            runD = dG; runCross = (gi >> 31) != 0;
            a0 = r0; a1 = r1; a2 = r2; a3 = r3;
        }
    }
    flush();
}

// ---------------------------------------------------------------------------
// node kernel (2-tile batched, 512 threads -> 16 waves/CU)
// ---------------------------------------------------------------------------
template<bool H16, bool L0, bool LAST>
__global__ void __launch_bounds__(512, 2)
node_kernel(const _Float16* __restrict__ hA,    // [N,128] (unused if L0)
            const void* __restrict__ hNv,       // [N,128] f16 or f32
            const _Float16* __restrict__ W2T,   // [128,K2]
            const float* __restrict__ embW2,    // [30,128] (L0 only)
            const int* __restrict__ gt,         // (L0 only)
            const int* __restrict__ n2g,
            _Float16* __restrict__ hOut,        // if !LAST
            float* __restrict__ fOut,           // if LAST
            float* __restrict__ readout,
            int N, int tilesPerWave, int nTiles, int layerOff)
{
    constexpr int K2  = L0 ? 128 : 256;
    constexpr int KCA = L0 ? 0 : 4;
    constexpr int KC  = K2 / 32;
    constexpr int SPR = K2 / 8;
    __shared__ __align__(16) _Float16 lds[128 * K2];

    const int tid = threadIdx.x;
    for (int s = tid; s < 128 * SPR; s += 512) {
        const int row = s / SPR, seg = s % SPR;
        half8 v = *(const half8*)(W2T + (size_t)row * K2 + seg * 8);
        *(half8*)(&lds[row * K2 + ((seg ^ (row & 7)) * 8)]) = v;
    }
    __syncthreads();

    const int lane = tid & 63;
    const int wv   = tid >> 6;
    const int lRow = lane & 15;
    const int lGrp = lane >> 4;
    const int wave = blockIdx.x * 8 + wv;
    const int t0 = wave * tilesPerWave;
    const int t1 = min(t0 + tilesPerWave, nTiles);
    if (t0 >= t1) return;

    int gCur = -1; float racc[8];
#pragma unroll
    for (int jt = 0; jt < 8; ++jt) racc[jt] = 0.0f;

    auto loadA = [&](int i0, half8 (&afrag)[KC]) {
        const int iA = min(i0 + lRow, N - 1);
#pragma unroll
        for (int kc = 0; kc < KCA; ++kc)
            afrag[kc] = *(const half8*)(hA + (size_t)iA * 128 + kc * 32 + lGrp * 8);
        if (H16) {
            const _Float16* hN = (const _Float16*)hNv;
#pragma unroll
            for (int kc = KCA; kc < KC; ++kc)
                afrag[kc] = *(const half8*)(hN + (size_t)iA * 128 + (kc - KCA) * 32 + lGrp * 8);
        } else {
            const float* hN = (const float*)hNv;
#pragma unroll
            for (int kc = KCA; kc < KC; ++kc) {
                const float* p = hN + (size_t)iA * 128 + (kc - KCA) * 32 + lGrp * 8;
                floatx4 f0 = *(const floatx4*)(p);
                floatx4 f1 = *(const floatx4*)(p + 4);
                half8 a;
#pragma unroll
                for (int i = 0; i < 4; ++i) { a[i] = f2h(f0[i]); a[i + 4] = f2h(f1[i]); }
                afrag[kc] = a;
            }
        }
    };

    auto epilogue = [&](int i0, floatx4 (&acc)[8]) {
        if (L0) {
#pragma unroll
            for (int r = 0; r < 4; ++r) {
                const int i = min(i0 + lGrp * 4 + r, N - 1);
                const int g_t = gt[i];
#pragma unroll
                for (int jt = 0; jt < 8; ++jt)
                    acc[jt][r] += embW2[(size_t)g_t * 128 + jt * 16 + lRow];
            }
        }
        float scl[4];
#pragma unroll
        for (int r = 0; r < 4; ++r) {
            float s = 0.f;
#pragma unroll
            for (int jt = 0; jt < 8; ++jt) {
                float v = fmaxf(acc[jt][r], 0.0f);
                s += v * v;
            }
#pragma unroll
            for (int m = 1; m <= 8; m <<= 1) s += __shfl_xor(s, m);
            scl[r] = 1.0f / fmaxf(sqrtf(s), 1e-12f);
        }
#pragma unroll
        for (int r = 0; r < 4; ++r) {
            const int i = i0 + lGrp * 4 + r;
            if (i < N) {
#pragma unroll
                for (int jt = 0; jt < 8; ++jt) {
                    float v = fmaxf(acc[jt][r], 0.0f) * scl[r];
                    if (LAST) fOut[(size_t)i * 128 + jt * 16 + lRow] = v;
                    else      hOut[(size_t)i * 128 + jt * 16 + lRow] = f2h(v);
                }
            }
        }
        const int gFirst = n2g[min(i0, N - 1)];
        const int gLast  = n2g[min(i0 + 15, N - 1)];
        if (gFirst == gLast && i0 + 15 < N) {
            if (gFirst != gCur) {
                if (gCur >= 0 && lane < 16) {
#pragma unroll
                    for (int jt = 0; jt < 8; ++jt)
                        unsafeAtomicAdd(&readout[(size_t)gCur * 384 + layerOff + jt * 16 + lane], racc[jt]);
                }
                gCur = gFirst;
#pragma unroll
                for (int jt = 0; jt < 8; ++jt) racc[jt] = 0.0f;
            }
#pragma unroll
            for (int jt = 0; jt < 8; ++jt) {
                float t = 0.f;
#pragma unroll
                for (int r = 0; r < 4; ++r) t += fmaxf(acc[jt][r], 0.0f) * scl[r];
                t += __shfl_xor(t, 16);
                t += __shfl_xor(t, 32);
                racc[jt] += t;
            }
        } else {
            if (gCur >= 0 && lane < 16) {
#pragma unroll
                for (int jt = 0; jt < 8; ++jt)
                    unsafeAtomicAdd(&readout[(size_t)gCur * 384 + layerOff + jt * 16 + lane], racc[jt]);
            }
            gCur = -1;
#pragma unroll
            for (int jt = 0; jt < 8; ++jt) racc[jt] = 0.0f;
#pragma unroll
            for (int r = 0; r < 4; ++r) {
                const int i = i0 + lGrp * 4 + r;
                if (i < N) {
                    const int g = n2g[i];
#pragma unroll
                    for (int jt = 0; jt < 8; ++jt) {
                        float v = fmaxf(acc[jt][r], 0.0f) * scl[r];
                        unsafeAtomicAdd(&readout[(size_t)g * 384 + layerOff + jt * 16 + lRow], v);
                    }
                }
            }
        }
    };

    for (int tile = t0; tile < t1; tile += 2) {
        const bool has2 = (tile + 1 < t1);
        const int i0a = tile * 16;
        const int i0b = has2 ? (tile + 1) * 16 : i0a;

        half8 afA[KC], afB[KC];
        loadA(i0a, afA);
        loadA(i0b, afB);

        floatx4 accA[8] = {}, accB[8] = {};
#pragma unroll
        for (int jt = 0; jt < 8; ++jt) {
            const int rb = (jt * 16 + lRow) * K2;
            const int sw = (jt * 16 + lRow) & 7;
#pragma unroll
            for (int kc = 0; kc < KC; ++kc) {
                half8 b = *(const half8*)(&lds[rb + (((kc * 4 + lGrp) ^ sw) * 8)]);
                accA[jt] = __builtin_amdgcn_mfma_f32_16x16x32_f16(afA[kc], b, accA[jt], 0, 0, 0);
                accB[jt] = __builtin_amdgcn_mfma_f32_16x16x32_f16(afB[kc], b, accB[jt], 0, 0, 0);
            }
        }
        epilogue(i0a, accA);
        if (has2) epilogue(i0b, accB);
    }
    if (gCur >= 0 && lane < 16) {
#pragma unroll
        for (int jt = 0; jt < 8; ++jt)
            unsafeAtomicAdd(&readout[(size_t)gCur * 384 + layerOff + jt * 16 + lane], racc[jt]);
    }
}

// ---------------------------------------------------------------------------
extern "C" void kernel_launch(void* const* d_in, const int* in_sizes, int n_in,
                              void* d_out, int out_size, void* d_ws, size_t ws_size,
                              hipStream_t stream)
{
    const int*   gate_type = (const int*)d_in[0];
    const int*   src  = (const int*)d_in[1];
    const int*   dst  = (const int*)d_in[2];
    const float* wE   = (const float*)d_in[3];
    const int*   n2g  = (const int*)d_in[4];
    const float* emb  = (const float*)d_in[5];
    const float* W1_0 = (const float*)d_in[6];
    const float* b1_0 = (const float*)d_in[7];
    const float* W2_0 = (const float*)d_in[8];
    const float* W1_1 = (const float*)d_in[9];
    const float* b1_1 = (const float*)d_in[10];
    const float* W2_1 = (const float*)d_in[11];
    const float* W1_2 = (const float*)d_in[12];
    const float* b1_2 = (const float*)d_in[13];
    const float* W2_2 = (const float*)d_in[14];

    const int N = in_sizes[0];
    const int E = in_sizes[1];
    const int NGT = in_sizes[5] / 64;
    const int cap = (E + 3 * N + 15) & ~15;

    char* ws = (char*)d_ws;
    size_t off = 0;
    auto alloc = [&](size_t bytes) { void* p = ws + off; off = (off + bytes + 255) & ~255ULL; return p; };
    _Float16* hBuf  = (_Float16*)alloc((size_t)N * 128 * 2);
    int4*     eData = (int4*)alloc(((size_t)cap + 16) * 16);
    unsigned* gInfo = (unsigned*)alloc(((size_t)cap / 4 + 4) * 4);
    int*      cnt   = (int*)alloc((size_t)N * 4);
    int*      offP  = (int*)alloc((size_t)N * 4);
    int*      cur   = (int*)alloc((size_t)N * 4);
    int*      bSums = (int*)alloc(256 * 4);
    _Float16* W1T1  = (_Float16*)alloc((size_t)128 * 128 * 2);
    _Float16* W1T2  = (_Float16*)alloc((size_t)128 * 128 * 2);
    _Float16* W2T0  = (_Float16*)alloc((size_t)128 * 128 * 2);
    _Float16* W2T1  = (_Float16*)alloc((size_t)128 * 256 * 2);
    _Float16* W2T2  = (_Float16*)alloc((size_t)128 * 256 * 2);
    _Float16* Wwh0  = (_Float16*)alloc((size_t)3 * 128 * 2);
    _Float16* Wwh1  = (_Float16*)alloc((size_t)3 * 128 * 2);
    _Float16* Wwh2  = (_Float16*)alloc((size_t)3 * 128 * 2);
    _Float16* eW1b  = (_Float16*)alloc((size_t)(NGT + 1) * 128 * 2);
    float*    eW2   = (float*)alloc((size_t)NGT * 128 * 4);
    _Float16* hW1b  = (_Float16*)alloc(((size_t)N + 1) * 128 * 2);
    size_t hn16_off = off;
    const bool h16 = (ws_size >= hn16_off + (size_t)N * 128 * 2 + 256);
    _Float16* hN16 = (_Float16*)alloc((size_t)N * 128 * 2);

    float* readout = (float*)d_out + (size_t)N * 128;  // [G,384]
    void*  hN      = h16 ? (void*)hN16 : (void*)d_out;

    const int nGroups = cap / 4;
    const int nTiles  = (N + 15) / 16;
    const int EB = 2048;                                 // edgeW blocks (4 waves)
    const int gpw = (nGroups + EB * 4 - 1) / (EB * 4);
    const int NB = 256;                                  // node blocks (8 waves)
    const int tpwN = (nTiles + NB * 8 - 1) / (NB * 8);
    const int HB = 256;                                  // hw1 blocks (8 waves)
    const int tpwH = (nTiles + HB * 8 - 1) / (HB * 8);
    const int nb = (N + 1023) / 1024;

    // ---- init + counting sort (padded to 4 per dst, 16B/slot payload) ----
    hipMemsetAsync(cnt, 0, (size_t)N * 4, stream);
    hipMemsetAsync(cur, 0, (size_t)N * 4, stream);
    hipMemsetAsync(hW1b + (size_t)N * 128, 0, 256, stream);   // zero pad row
    fill_dummy_kernel<<<(cap + 16 + 255) / 256, 256, 0, stream>>>(eData, cap + 16, N, NGT);
    hist_kernel<<<(E + 255) / 256, 256, 0, stream>>>(dst, cnt, E);
    scan1p_kernel<<<nb, 256, 0, stream>>>(cnt, offP, N, bSums);
    scan2_kernel<<<1, 256, 0, stream>>>(bSums, nb);
    scan3_kernel<<<nb, 256, 0, stream>>>(offP, N, bSums);
    scatter_kernel<<<(E + 255) / 256, 256, 0, stream>>>(src, dst, wE, gate_type,
                                                        offP, cur, eData, E);
    ginfo_kernel<<<(nGroups + 255) / 256, 256, 0, stream>>>(eData, cnt, offP, gInfo,
                                                            nGroups, N, gpw);

    // ---- weight prep ----
    embW1_kernel<<<((NGT + 1) * 128 + 255) / 256, 256, 0, stream>>>(emb, W1_0, b1_0, eW1b, NGT);
    embW2_kernel<<<(NGT * 128 + 255) / 256, 256, 0, stream>>>(emb, W2_0, eW2, NGT);
    wprep_kernel<<<(128 * 128 + 255) / 256, 256, 0, stream>>>(W1_1, W1T1, 128, 128);
    wprep_kernel<<<(128 * 128 + 255) / 256, 256, 0, stream>>>(W1_2, W1T2, 128, 128);
    wprep_kernel<<<(128 * 128 + 255) / 256, 256, 0, stream>>>(W2_0 + (size_t)64 * 128, W2T0, 128, 128);
    wprep_kernel<<<(128 * 256 + 255) / 256, 256, 0, stream>>>(W2_1, W2T1, 256, 256);
    wprep_kernel<<<(128 * 256 + 255) / 256, 256, 0, stream>>>(W2_2, W2T2, 256, 256);
    wwprep_kernel<<<2, 256, 0, stream>>>(W1_0, 64, Wwh0);
    wwprep_kernel<<<2, 256, 0, stream>>>(W1_1, 128, Wwh1);
    wwprep_kernel<<<2, 256, 0, stream>>>(W1_2, 128, Wwh2);

    if (h16) {
        hipMemsetAsync(readout, 0, (size_t)(out_size - N * 128) * 4, stream);
        hipMemsetAsync(hN16, 0, (size_t)N * 128 * 2, stream);
        // layer 0
        edgeW_kernel<true, true><<<EB, 256, 0, stream>>>(eW1b, Wwh0, eData, gInfo, hN, gpw, nGroups);
        node_kernel<true, true, false><<<NB, 512, 0, stream>>>(nullptr, hN, W2T0, eW2, gate_type, n2g,
                                                               hBuf, nullptr, readout, N, tpwN, nTiles, 0);
        // layer 1
        hw1_kernel<<<HB, 512, 0, stream>>>(hBuf, W1T1, b1_1, hW1b, N, tpwH, nTiles);
        hipMemsetAsync(hN16, 0, (size_t)N * 128 * 2, stream);
        edgeW_kernel<false, true><<<EB, 256, 0, stream>>>(hW1b, Wwh1, eData, gInfo, hN, gpw, nGroups);
        node_kernel<true, false, false><<<NB, 512, 0, stream>>>(hBuf, hN, W2T1, nullptr, nullptr, n2g,
                                                                hBuf, nullptr, readout, N, tpwN, nTiles, 128);
        // layer 2
        hw1_kernel<<<HB, 512, 0, stream>>>(hBuf, W1T2, b1_2, hW1b, N, tpwH, nTiles);
        hipMemsetAsync(hN16, 0, (size_t)N * 128 * 2, stream);
        edgeW_kernel<false, true><<<EB, 256, 0, stream>>>(hW1b, Wwh2, eData, gInfo, hN, gpw, nGroups);
        node_kernel<true, false, true><<<NB, 512, 0, stream>>>(hBuf, hN, W2T2, nullptr, nullptr, n2g,
                                                               nullptr, (float*)d_out, readout, N, tpwN, nTiles, 256);
    } else {
        hipMemsetAsync(d_out, 0, (size_t)out_size * 4, stream);
        // layer 0
        edgeW_kernel<true, false><<<EB, 256, 0, stream>>>(eW1b, Wwh0, eData, gInfo, hN, gpw, nGroups);
        node_kernel<false, true, false><<<NB, 512, 0, stream>>>(nullptr, hN, W2T0, eW2, gate_type, n2g,
                                                                hBuf, nullptr, readout, N, tpwN, nTiles, 0);
        // layer 1
        hw1_kernel<<<HB, 512, 0, stream>>>(hBuf, W1T1, b1_1, hW1b, N, tpwH, nTiles);
        hipMemsetAsync(d_out, 0, (size_t)N * 128 * 4, stream);
        edgeW_kernel<false, false><<<EB, 256, 0, stream>>>(hW1b, Wwh1, eData, gInfo, hN, gpw, nGroups);
        node_kernel<false, false, false><<<NB, 512, 0, stream>>>(hBuf, hN, W2T1, nullptr, nullptr, n2g,
                                                                 hBuf, nullptr, readout, N, tpwN, nTiles, 128);
        // layer 2
        hw1_kernel<<<HB, 512, 0, stream>>>(hBuf, W1T2, b1_2, hW1b, N, tpwH, nTiles);
        hipMemsetAsync(d_out, 0, (size_t)N * 128 * 4, stream);
        edgeW_kernel<false, false><<<EB, 256, 0, stream>>>(hW1b, Wwh2, eData, gInfo, hN, gpw, nGroups);
        node_kernel<false, false, true><<<NB, 512, 0, stream>>>(hBuf, hN, W2T2, nullptr, nullptr, n2g,
                                                                nullptr, (float*)d_out, readout, N, tpwN, nTiles, 256);
    }
}

// Round 17
// 498.728 us; speedup vs baseline: 1.1018x; 1.0116x over previous
//
#include <hip/hip_runtime.h>
#include <hip/hip_bf16.h>
#include <hip/hip_fp16.h>

typedef _Float16 half8 __attribute__((ext_vector_type(8)));
typedef _Float16 half4 __attribute__((ext_vector_type(4)));
typedef _Float16 h2    __attribute__((ext_vector_type(2)));
typedef float floatx4 __attribute__((ext_vector_type(4)));

__device__ __forceinline__ _Float16 f2h(float f) { return (_Float16)f; }

// eData slot (16B): {src | gt<<24, dst, w01 (2xf16), w2_one (2xf16)}
// dummy slot: {N | NGT<<24, N, 0, 0};  groups are 4 edges (pad-to-4 per dst)

// ---------------------------------------------------------------------------
__global__ void fill_dummy_kernel(int4* __restrict__ eData, int cap, int N, int NGT)
{
    int i = blockIdx.x * 256 + threadIdx.x;
    if (i < cap) { int4 v = {N | (NGT << 24), N, 0, 0}; eData[i] = v; }
}

// hist + per-edge arrival rank (removes the atomic from scatter)
__global__ void histrank_kernel(const int* __restrict__ dst, int* __restrict__ cnt,
                                int* __restrict__ rank, int E)
{
    int e = blockIdx.x * 256 + threadIdx.x;
    if (e < E) rank[e] = atomicAdd(&cnt[dst[e]], 1);
}

// exclusive scan of per-node counts PADDED to multiple of 4 -> offP
__global__ void scan1p_kernel(const int* __restrict__ cnt, int* __restrict__ offP,
                              int n, int* __restrict__ blockSums)
{
    __shared__ int sm[256];
    const int t = threadIdx.x;
    const int base = blockIdx.x * 1024 + t * 4;
    int v[4]; int s = 0;
#pragma unroll
    for (int i = 0; i < 4; ++i) {
        v[i] = (base + i < n) ? ((cnt[base + i] + 3) & ~3) : 0;
        s += v[i];
    }
    sm[t] = s; __syncthreads();
#pragma unroll
    for (int off = 1; off < 256; off <<= 1) {
        int y = (t >= off) ? sm[t - off] : 0;
        __syncthreads();
        if (t >= off) sm[t] += y;
        __syncthreads();
    }
    int excl = sm[t] - s;
    if (t == 255) blockSums[blockIdx.x] = sm[255];
    int run = excl;
#pragma unroll
    for (int i = 0; i < 4; ++i) {
        if (base + i < n) offP[base + i] = run;
        run += v[i];
    }
}

__global__ void scan2_kernel(int* __restrict__ blockSums, int nb)
{
    __shared__ int sm[256];
    const int t = threadIdx.x;
    int s = (t < nb) ? blockSums[t] : 0;
    sm[t] = s; __syncthreads();
#pragma unroll
    for (int off = 1; off < 256; off <<= 1) {
        int y = (t >= off) ? sm[t - off] : 0;
        __syncthreads();
        if (t >= off) sm[t] += y;
        __syncthreads();
    }
    if (t < nb) blockSums[t] = sm[t] - s;
}

__global__ void scan3_kernel(int* __restrict__ offP, int n, const int* __restrict__ blockSums)
{
    const int base = blockIdx.x * 1024 + threadIdx.x * 4;
    const int add = blockSums[blockIdx.x];
#pragma unroll
    for (int i = 0; i < 4; ++i)
        if (base + i < n) offP[base + i] += add;
}

// single 16B store per edge into the sorted slot (rank precomputed, no atomic)
__global__ void scatter_kernel(const int* __restrict__ src, const int* __restrict__ dst,
                               const float* __restrict__ w, const int* __restrict__ gt,
                               const int* __restrict__ offP, const int* __restrict__ rank,
                               int4* __restrict__ eData, int E)
{
    int e = blockIdx.x * 256 + threadIdx.x;
    if (e >= E) return;
    int d = dst[e];
    int p = offP[d] + rank[e];
    int s = src[e];
    h2 w01 = { f2h(w[(size_t)e * 3 + 0]), f2h(w[(size_t)e * 3 + 1]) };
    h2 w2o = { f2h(w[(size_t)e * 3 + 2]), (_Float16)1.0f };
    int4 v = { s | (gt[s] << 24), d,
               __builtin_bit_cast(int, w01), __builtin_bit_cast(int, w2o) };
    eData[p] = v;
}

// per-group info: dG (24b) | cross-wave flag (bit31); dummy group = 0xFFFFFFFF
__global__ void ginfo_kernel(const int4* __restrict__ eData,
                             const int* __restrict__ cnt, const int* __restrict__ offP,
                             unsigned* __restrict__ gInfo,
                             int nGroups, int N, int gpw)
{
    int g = blockIdx.x * 256 + threadIdx.x;
    if (g >= nGroups) return;
    const int* ei = (const int*)eData;
    int d = ei[16 * g + 1];
    if (d >= N) { gInfo[g] = 0xFFFFFFFFu; return; }
    int cntP = (cnt[d] + 3) & ~3;
    int gA = offP[d] >> 2;
    int gB = gA + (cntP >> 2) - 1;
    bool cross = (gA / gpw) != (gB / gpw);
    gInfo[g] = (unsigned)d | (cross ? 0x80000000u : 0u);
}

// deg-0 rows (zero once) and cross-wave rows (zero per layer)
__global__ void nodelists_kernel(const int* __restrict__ cnt, const int* __restrict__ offP,
                                 int N, int gpw,
                                 int* __restrict__ zCnt, int* __restrict__ zList,
                                 int* __restrict__ cCnt, int* __restrict__ cList)
{
    int d = blockIdx.x * 256 + threadIdx.x;
    if (d >= N) return;
    int c = cnt[d];
    if (c == 0) { zList[atomicAdd(zCnt, 1)] = d; return; }
    int cntP = (c + 3) & ~3;
    int gA = offP[d] >> 2;
    int gB = gA + (cntP >> 2) - 1;
    if (gA / gpw != gB / gpw) cList[atomicAdd(cCnt, 1)] = d;
}

__global__ void zero_rows_kernel(const int* __restrict__ list, const int* __restrict__ cntPtr,
                                 _Float16* __restrict__ hN)
{
    const int n = *cntPtr * 16;              // 16 x 16B chunks per 256B row
    for (int i = blockIdx.x * 256 + threadIdx.x; i < n; i += gridDim.x * 256) {
        const int row = list[i >> 4], c = (i & 15) * 8;
        int4 zz = {0, 0, 0, 0};
        *(int4*)(hN + (size_t)row * 128 + c) = zz;
    }
}

// ---------------------------------------------------------------------------
// ONE kernel for all weight prep (replaces 10 tiny dispatches)
// segments: embW1b | embW2 | W1T1 | W1T2 | W2T0 | W2T1 | W2T2 | Wwh0|1|2
// ---------------------------------------------------------------------------
__global__ void prep_all_kernel(const float* __restrict__ emb,
                                const float* __restrict__ W1_0, const float* __restrict__ b1_0,
                                const float* __restrict__ b1_1, const float* __restrict__ b1_2,
                                const float* __restrict__ W1_1, const float* __restrict__ W1_2,
                                const float* __restrict__ W2_0, const float* __restrict__ W2_1,
                                const float* __restrict__ W2_2,
                                _Float16* __restrict__ eW1b, float* __restrict__ eW2,
                                _Float16* __restrict__ W1T1, _Float16* __restrict__ W1T2,
                                _Float16* __restrict__ W2T0, _Float16* __restrict__ W2T1,
                                _Float16* __restrict__ W2T2,
                                _Float16* __restrict__ Wwh0, _Float16* __restrict__ Wwh1,
                                _Float16* __restrict__ Wwh2, int NGT)
{
    int idx = blockIdx.x * 256 + threadIdx.x;
    const int nE1 = (NGT + 1) * 128;
    if (idx < nE1) {                                    // embW1b (+ zero pad row)
        int g = idx >> 7, f = idx & 127;
        float s = 0.0f;
        if (g < NGT) {
            s = b1_0[f];
            for (int k = 0; k < 64; ++k) s += emb[g * 64 + k] * W1_0[(size_t)k * 128 + f];
        }
        eW1b[idx] = f2h(s);
        return;
    }
    idx -= nE1;
    const int nE2 = NGT * 128;
    if (idx < nE2) {                                    // embW2
        int g = idx >> 7, f = idx & 127;
        float s = 0.0f;
        for (int k = 0; k < 64; ++k) s += emb[g * 64 + k] * W2_0[(size_t)k * 128 + f];
        eW2[idx] = s;
        return;
    }
    idx -= nE2;
    if (idx < 16384) { int f = idx >> 7, k = idx & 127;            // W1T1
        W1T1[idx] = f2h(W1_1[(size_t)k * 128 + f]); return; }
    idx -= 16384;
    if (idx < 16384) { int f = idx >> 7, k = idx & 127;            // W1T2
        W1T2[idx] = f2h(W1_2[(size_t)k * 128 + f]); return; }
    idx -= 16384;
    if (idx < 16384) { int f = idx >> 7, k = idx & 127;            // W2T0 (rows 64..191)
        W2T0[idx] = f2h(W2_0[(size_t)(64 + k) * 128 + f]); return; }
    idx -= 16384;
    if (idx < 32768) { int f = idx >> 8, k = idx & 255;            // W2T1
        W2T1[idx] = f2h(W2_1[(size_t)k * 128 + f]); return; }
    idx -= 32768;
    if (idx < 32768) { int f = idx >> 8, k = idx & 255;            // W2T2
        W2T2[idx] = f2h(W2_2[(size_t)k * 128 + f]); return; }
    idx -= 32768;
    if (idx < 384) { Wwh0[idx] = f2h(W1_0[(size_t)(64 + idx / 128) * 128 + (idx & 127)]); return; }
    idx -= 384;
    if (idx < 384) { Wwh1[idx] = f2h(W1_1[(size_t)(128 + idx / 128) * 128 + (idx & 127)]); return; }
    idx -= 384;
    if (idx < 384) { Wwh2[idx] = f2h(W1_2[(size_t)(128 + idx / 128) * 128 + (idx & 127)]); return; }
}

// ---------------------------------------------------------------------------
// hW1b = h @ W1[:128] + b1  (dense, per-node; feeds the edge kernel)
// ---------------------------------------------------------------------------
__global__ void __launch_bounds__(512, 2)
hw1_kernel(const _Float16* __restrict__ hA,   // [N,128]
           const _Float16* __restrict__ WT,   // [128 outcol, 128 k] f16
           const float* __restrict__ b1,
           _Float16* __restrict__ out,        // [(N+1),128]
           int N, int tilesPerWave, int nTiles)
{
    __shared__ __align__(16) _Float16 lds[128 * 128];
    const int tid = threadIdx.x;
    for (int s = tid; s < 128 * 16; s += 512) {
        const int row = s / 16, seg = s % 16;
        half8 v = *(const half8*)(WT + (size_t)row * 128 + seg * 8);
        *(half8*)(&lds[row * 128 + ((seg ^ (row & 7)) * 8)]) = v;
    }
    __syncthreads();

    const int lane = tid & 63;
    const int wv   = tid >> 6;
    const int lRow = lane & 15;
    const int lGrp = lane >> 4;

    float b1v[8];
#pragma unroll
    for (int jt = 0; jt < 8; ++jt) b1v[jt] = b1[jt * 16 + lRow];

    const int wave = blockIdx.x * 8 + wv;
    const int t0 = wave * tilesPerWave;
    const int t1 = min(t0 + tilesPerWave, nTiles);

    for (int tile = t0; tile < t1; ++tile) {
        const int i0 = tile * 16;
        const int iA = min(i0 + lRow, N - 1);
        half8 a[4];
#pragma unroll
        for (int kc = 0; kc < 4; ++kc)
            a[kc] = *(const half8*)(hA + (size_t)iA * 128 + kc * 32 + lGrp * 8);

        floatx4 acc[8] = {};
#pragma unroll
        for (int jt = 0; jt < 8; ++jt) {
            const int row = jt * 16 + lRow;
            const int sw = row & 7;
#pragma unroll
            for (int kc = 0; kc < 4; ++kc) {
                half8 b = *(const half8*)(&lds[row * 128 + (((kc * 4 + lGrp) ^ sw) * 8)]);
                acc[jt] = __builtin_amdgcn_mfma_f32_16x16x32_f16(a[kc], b, acc[jt], 0, 0, 0);
            }
        }
#pragma unroll
        for (int r = 0; r < 4; ++r) {
            const int i = i0 + lGrp * 4 + r;
            if (i < N) {
#pragma unroll
                for (int jt = 0; jt < 8; ++jt)
                    out[(size_t)i * 128 + jt * 16 + lRow] = f2h(acc[jt][r] + b1v[jt]);
            }
        }
    }
}

// ---------------------------------------------------------------------------
// edge kernel: lane = (edge-slot = lane>>4, 8 cols = (lane&15)*8).
// Per 4-edge group: ONE 16B/lane eData load + ONE 16B/lane T row-read.
// Run-merge across same-dst groups; flush = reduce over edge-slots + one
// 16B/lane row store (atomics only for cross-wave dsts, gInfo bit31).
// ---------------------------------------------------------------------------
template<bool L0, bool H16>
__global__ void __launch_bounds__(256, 4)
edgeW_kernel(const _Float16* __restrict__ T,    // embW1b (L0) or hW1b
             const _Float16* __restrict__ Wwh,  // [3][128] f16
             const int4* __restrict__ eData,
             const unsigned* __restrict__ gInfo,
             void* __restrict__ hNv, int groupsPerWave, int nGroups)
{
    const int tid  = threadIdx.x;
    const int lane = tid & 63;
    const int wv   = tid >> 6;
    const int eidx = lane >> 4;          // edge slot 0..3 within group
    const int c8   = (lane & 15) * 8;    // 8 consecutive output cols

    const h2 z = {(_Float16)0.0f, (_Float16)0.0f};
    h2 w0[4], w1[4], w2[4];
#pragma unroll
    for (int j = 0; j < 4; ++j) {
        w0[j] = *(const h2*)(Wwh + 0 * 128 + c8 + 2 * j);
        w1[j] = *(const h2*)(Wwh + 1 * 128 + c8 + 2 * j);
        w2[j] = *(const h2*)(Wwh + 2 * 128 + c8 + 2 * j);
    }

    const int wave = blockIdx.x * 4 + wv;
    const int g0 = wave * groupsPerWave;
    const int g1 = min(g0 + groupsPerWave, nGroups);
    if (g0 >= g1) return;

    int runD = -1; bool runCross = false;
    h2 a0 = z, a1 = z, a2 = z, a3 = z;   // per-lane partials (own edge slot)

    auto flush = [&]() {
        if (runD < 0) return;
        h2 s0 = a0, s1 = a1, s2 = a2, s3 = a3;
#pragma unroll
        for (int m = 16; m <= 32; m <<= 1) {
            int t0_ = __shfl_xor(__builtin_bit_cast(int, s0), m);
            int t1_ = __shfl_xor(__builtin_bit_cast(int, s1), m);
            int t2_ = __shfl_xor(__builtin_bit_cast(int, s2), m);
            int t3_ = __shfl_xor(__builtin_bit_cast(int, s3), m);
            s0 = s0 + __builtin_bit_cast(h2, t0_);
            s1 = s1 + __builtin_bit_cast(h2, t1_);
            s2 = s2 + __builtin_bit_cast(h2, t2_);
            s3 = s3 + __builtin_bit_cast(h2, t3_);
        }
        if (lane < 16) {
            if (H16) {
                if (runCross) {
                    __half2* p = (__half2*)((__half*)hNv + (size_t)runD * 128 + c8);
                    unsafeAtomicAdd(p + 0, __builtin_bit_cast(__half2, s0));
                    unsafeAtomicAdd(p + 1, __builtin_bit_cast(__half2, s1));
                    unsafeAtomicAdd(p + 2, __builtin_bit_cast(__half2, s2));
                    unsafeAtomicAdd(p + 3, __builtin_bit_cast(__half2, s3));
                } else {
                    int4 pk = { __builtin_bit_cast(int, s0), __builtin_bit_cast(int, s1),
                                __builtin_bit_cast(int, s2), __builtin_bit_cast(int, s3) };
                    *(int4*)((__half*)hNv + (size_t)runD * 128 + c8) = pk;
                }
            } else {
                float f[8] = {(float)s0[0], (float)s0[1], (float)s1[0], (float)s1[1],
                              (float)s2[0], (float)s2[1], (float)s3[0], (float)s3[1]};
                float* p = (float*)hNv + (size_t)runD * 128 + c8;
                if (runCross) {
#pragma unroll
                    for (int j = 0; j < 8; ++j) unsafeAtomicAdd(p + j, f[j]);
                } else {
                    floatx4 q0 = {f[0], f[1], f[2], f[3]};
                    floatx4 q1 = {f[4], f[5], f[6], f[7]};
                    *(floatx4*)(p) = q0;
                    *(floatx4*)(p + 4) = q1;
                }
            }
        }
    };

    for (int g = g0; g < g1; ++g) {
        const unsigned gi = gInfo[g];
        if (gi == 0xFFFFFFFFu) break;    // dummy suffix begins
        const int dG = (int)(gi & 0xFFFFFFu);

        const int4 e = eData[g * 4 + eidx];              // 4 addrs / wave
        const int r_ = L0 ? (e.x >> 24) : (e.x & 0xFFFFFF);
        const half8 Tv = *(const half8*)(T + (size_t)r_ * 128 + c8);  // 4 rows / wave
        const h2 w01 = __builtin_bit_cast(h2, e.z);
        const h2 w2o = __builtin_bit_cast(h2, e.w);

        h2 m0 = h2{Tv[0], Tv[1]} + w01[0] * w0[0] + w01[1] * w1[0] + w2o[0] * w2[0];
        h2 m1 = h2{Tv[2], Tv[3]} + w01[0] * w0[1] + w01[1] * w1[1] + w2o[0] * w2[1];
        h2 m2 = h2{Tv[4], Tv[5]} + w01[0] * w0[2] + w01[1] * w1[2] + w2o[0] * w2[2];
        h2 m3 = h2{Tv[6], Tv[7]} + w01[0] * w0[3] + w01[1] * w1[3] + w2o[0] * w2[3];
        h2 r0 = __builtin_elementwise_max(m0, z);
        h2 r1 = __builtin_elementwise_max(m1, z);
        h2 r2 = __builtin_elementwise_max(m2, z);
        h2 r3 = __builtin_elementwise_max(m3, z);

        if (dG == runD) {
            a0 = a0 + r0; a1 = a1 + r1; a2 = a2 + r2; a3 = a3 + r3;
        } else {
            flush();
            runD = dG; runCross = (gi >> 31) != 0;
            a0 = r0; a1 = r1; a2 = r2; a3 = r3;
        }
    }
    flush();
}

// ---------------------------------------------------------------------------
// node kernel (2-tile batched, 512 threads -> 16 waves/CU)
// ---------------------------------------------------------------------------
template<bool H16, bool L0, bool LAST>
__global__ void __launch_bounds__(512, 2)
node_kernel(const _Float16* __restrict__ hA,    // [N,128] (unused if L0)
            const void* __restrict__ hNv,       // [N,128] f16 or f32
            const _Float16* __restrict__ W2T,   // [128,K2]
            const float* __restrict__ embW2,    // [30,128] (L0 only)
            const int* __restrict__ gt,         // (L0 only)
            const int* __restrict__ n2g,
            _Float16* __restrict__ hOut,        // if !LAST
            float* __restrict__ fOut,           // if LAST
            float* __restrict__ readout,
            int N, int tilesPerWave, int nTiles, int layerOff)
{
    constexpr int K2  = L0 ? 128 : 256;
    constexpr int KCA = L0 ? 0 : 4;
    constexpr int KC  = K2 / 32;
    constexpr int SPR = K2 / 8;
    __shared__ __align__(16) _Float16 lds[128 * K2];

    const int tid = threadIdx.x;
    for (int s = tid; s < 128 * SPR; s += 512) {
        const int row = s / SPR, seg = s % SPR;
        half8 v = *(const half8*)(W2T + (size_t)row * K2 + seg * 8);
        *(half8*)(&lds[row * K2 + ((seg ^ (row & 7)) * 8)]) = v;
    }
    __syncthreads();

    const int lane = tid & 63;
    const int wv   = tid >> 6;
    const int lRow = lane & 15;
    const int lGrp = lane >> 4;
    const int wave = blockIdx.x * 8 + wv;
    const int t0 = wave * tilesPerWave;
    const int t1 = min(t0 + tilesPerWave, nTiles);
    if (t0 >= t1) return;

    int gCur = -1; float racc[8];
#pragma unroll
    for (int jt = 0; jt < 8; ++jt) racc[jt] = 0.0f;

    auto loadA = [&](int i0, half8 (&afrag)[KC]) {
        const int iA = min(i0 + lRow, N - 1);
#pragma unroll
        for (int kc = 0; kc < KCA; ++kc)
            afrag[kc] = *(const half8*)(hA + (size_t)iA * 128 + kc * 32 + lGrp * 8);
        if (H16) {
            const _Float16* hN = (const _Float16*)hNv;
#pragma unroll
            for (int kc = KCA; kc < KC; ++kc)
                afrag[kc] = *(const half8*)(hN + (size_t)iA * 128 + (kc - KCA) * 32 + lGrp * 8);
        } else {
            const float* hN = (const float*)hNv;
#pragma unroll
            for (int kc = KCA; kc < KC; ++kc) {
                const float* p = hN + (size_t)iA * 128 + (kc - KCA) * 32 + lGrp * 8;
                floatx4 f0 = *(const floatx4*)(p);
                floatx4 f1 = *(const floatx4*)(p + 4);
                half8 a;
#pragma unroll
                for (int i = 0; i < 4; ++i) { a[i] = f2h(f0[i]); a[i + 4] = f2h(f1[i]); }
                afrag[kc] = a;
            }
        }
    };

    auto epilogue = [&](int i0, floatx4 (&acc)[8]) {
        if (L0) {
#pragma unroll
            for (int r = 0; r < 4; ++r) {
                const int i = min(i0 + lGrp * 4 + r, N - 1);
                const int g_t = gt[i];
#pragma unroll
                for (int jt = 0; jt < 8; ++jt)
                    acc[jt][r] += embW2[(size_t)g_t * 128 + jt * 16 + lRow];
            }
        }
        float scl[4];
#pragma unroll
        for (int r = 0; r < 4; ++r) {
            float s = 0.f;
#pragma unroll
            for (int jt = 0; jt < 8; ++jt) {
                float v = fmaxf(acc[jt][r], 0.0f);
                s += v * v;
            }
#pragma unroll
            for (int m = 1; m <= 8; m <<= 1) s += __shfl_xor(s, m);
            scl[r] = 1.0f / fmaxf(sqrtf(s), 1e-12f);
        }
#pragma unroll
        for (int r = 0; r < 4; ++r) {
            const int i = i0 + lGrp * 4 + r;
            if (i < N) {
#pragma unroll
                for (int jt = 0; jt < 8; ++jt) {
                    float v = fmaxf(acc[jt][r], 0.0f) * scl[r];
                    if (LAST) fOut[(size_t)i * 128 + jt * 16 + lRow] = v;
                    else      hOut[(size_t)i * 128 + jt * 16 + lRow] = f2h(v);
                }
            }
        }
        const int gFirst = n2g[min(i0, N - 1)];
        const int gLast  = n2g[min(i0 + 15, N - 1)];
        if (gFirst == gLast && i0 + 15 < N) {
            if (gFirst != gCur) {
                if (gCur >= 0 && lane < 16) {
#pragma unroll
                    for (int jt = 0; jt < 8; ++jt)
                        unsafeAtomicAdd(&readout[(size_t)gCur * 384 + layerOff + jt * 16 + lane], racc[jt]);
                }
                gCur = gFirst;
#pragma unroll
                for (int jt = 0; jt < 8; ++jt) racc[jt] = 0.0f;
            }
#pragma unroll
            for (int jt = 0; jt < 8; ++jt) {
                float t = 0.f;
#pragma unroll
                for (int r = 0; r < 4; ++r) t += fmaxf(acc[jt][r], 0.0f) * scl[r];
                t += __shfl_xor(t, 16);
                t += __shfl_xor(t, 32);
                racc[jt] += t;
            }
        } else {
            if (gCur >= 0 && lane < 16) {
#pragma unroll
                for (int jt = 0; jt < 8; ++jt)
                    unsafeAtomicAdd(&readout[(size_t)gCur * 384 + layerOff + jt * 16 + lane], racc[jt]);
            }
            gCur = -1;
#pragma unroll
            for (int jt = 0; jt < 8; ++jt) racc[jt] = 0.0f;
#pragma unroll
            for (int r = 0; r < 4; ++r) {
                const int i = i0 + lGrp * 4 + r;
                if (i < N) {
                    const int g = n2g[i];
#pragma unroll
                    for (int jt = 0; jt < 8; ++jt) {
                        float v = fmaxf(acc[jt][r], 0.0f) * scl[r];
                        unsafeAtomicAdd(&readout[(size_t)g * 384 + layerOff + jt * 16 + lRow], v);
                    }
                }
            }
        }
    };

    for (int tile = t0; tile < t1; tile += 2) {
        const bool has2 = (tile + 1 < t1);
        const int i0a = tile * 16;
        const int i0b = has2 ? (tile + 1) * 16 : i0a;

        half8 afA[KC], afB[KC];
        loadA(i0a, afA);
        loadA(i0b, afB);

        floatx4 accA[8] = {}, accB[8] = {};
#pragma unroll
        for (int jt = 0; jt < 8; ++jt) {
            const int rb = (jt * 16 + lRow) * K2;
            const int sw = (jt * 16 + lRow) & 7;
#pragma unroll
            for (int kc = 0; kc < KC; ++kc) {
                half8 b = *(const half8*)(&lds[rb + (((kc * 4 + lGrp) ^ sw) * 8)]);
                accA[jt] = __builtin_amdgcn_mfma_f32_16x16x32_f16(afA[kc], b, accA[jt], 0, 0, 0);
                accB[jt] = __builtin_amdgcn_mfma_f32_16x16x32_f16(afB[kc], b, accB[jt], 0, 0, 0);
            }
        }
        epilogue(i0a, accA);
        if (has2) epilogue(i0b, accB);
    }
    if (gCur >= 0 && lane < 16) {
#pragma unroll
        for (int jt = 0; jt < 8; ++jt)
            unsafeAtomicAdd(&readout[(size_t)gCur * 384 + layerOff + jt * 16 + lane], racc[jt]);
    }
}

// ---------------------------------------------------------------------------
extern "C" void kernel_launch(void* const* d_in, const int* in_sizes, int n_in,
                              void* d_out, int out_size, void* d_ws, size_t ws_size,
                              hipStream_t stream)
{
    const int*   gate_type = (const int*)d_in[0];
    const int*   src  = (const int*)d_in[1];
    const int*   dst  = (const int*)d_in[2];
    const float* wE   = (const float*)d_in[3];
    const int*   n2g  = (const int*)d_in[4];
    const float* emb  = (const float*)d_in[5];
    const float* W1_0 = (const float*)d_in[6];
    const float* b1_0 = (const float*)d_in[7];
    const float* W2_0 = (const float*)d_in[8];
    const float* W1_1 = (const float*)d_in[9];
    const float* b1_1 = (const float*)d_in[10];
    const float* W2_1 = (const float*)d_in[11];
    const float* W1_2 = (const float*)d_in[12];
    const float* b1_2 = (const float*)d_in[13];
    const float* W2_2 = (const float*)d_in[14];

    const int N = in_sizes[0];
    const int E = in_sizes[1];
    const int NGT = in_sizes[5] / 64;
    const int cap = (E + 3 * N + 15) & ~15;

    char* ws = (char*)d_ws;
    size_t off = 0;
    auto alloc = [&](size_t bytes) { void* p = ws + off; off = (off + bytes + 255) & ~255ULL; return p; };
    _Float16* hBuf  = (_Float16*)alloc((size_t)N * 128 * 2);
    int4*     eData = (int4*)alloc(((size_t)cap + 16) * 16);
    unsigned* gInfo = (unsigned*)alloc(((size_t)cap / 4 + 4) * 4);
    int*      cnt   = (int*)alloc((size_t)N * 4);
    int*      offP  = (int*)alloc((size_t)N * 4);
    int*      rank  = (int*)alloc((size_t)E * 4);
    int*      bSums = (int*)alloc(256 * 4);
    int*      zCnts = (int*)alloc(256);           // [0]=deg0 count, [1]=cross count
    int*      zList = (int*)alloc((size_t)N * 4);
    int*      cList = (int*)alloc((size_t)N * 4);
    _Float16* W1T1  = (_Float16*)alloc((size_t)128 * 128 * 2);
    _Float16* W1T2  = (_Float16*)alloc((size_t)128 * 128 * 2);
    _Float16* W2T0  = (_Float16*)alloc((size_t)128 * 128 * 2);
    _Float16* W2T1  = (_Float16*)alloc((size_t)128 * 256 * 2);
    _Float16* W2T2  = (_Float16*)alloc((size_t)128 * 256 * 2);
    _Float16* Wwh0  = (_Float16*)alloc((size_t)3 * 128 * 2);
    _Float16* Wwh1  = (_Float16*)alloc((size_t)3 * 128 * 2);
    _Float16* Wwh2  = (_Float16*)alloc((size_t)3 * 128 * 2);
    _Float16* eW1b  = (_Float16*)alloc((size_t)(NGT + 1) * 128 * 2);
    float*    eW2   = (float*)alloc((size_t)NGT * 128 * 4);
    _Float16* hW1b  = (_Float16*)alloc(((size_t)N + 1) * 128 * 2);
    size_t hn16_off = off;
    const bool h16 = (ws_size >= hn16_off + (size_t)N * 128 * 2 + 256);
    _Float16* hN16 = (_Float16*)alloc((size_t)N * 128 * 2);

    float* readout = (float*)d_out + (size_t)N * 128;  // [G,384]
    void*  hN      = h16 ? (void*)hN16 : (void*)d_out;

    const int nGroups = cap / 4;
    const int nTiles  = (N + 15) / 16;
    const int EB = 2048;                                 // edgeW blocks (4 waves)
    const int gpw = (nGroups + EB * 4 - 1) / (EB * 4);
    const int NB = 256;                                  // node blocks (8 waves)
    const int tpwN = (nTiles + NB * 8 - 1) / (NB * 8);
    const int HB = 256;                                  // hw1 blocks (8 waves)
    const int tpwH = (nTiles + HB * 8 - 1) / (HB * 8);
    const int nb = (N + 1023) / 1024;
    const int prepTot = (NGT + 1) * 128 + NGT * 128 + 3 * 16384 + 2 * 32768 + 3 * 384;

    // ---- init + counting sort (padded to 4 per dst, 16B/slot payload) ----
    hipMemsetAsync(cnt, 0, (size_t)N * 4, stream);
    hipMemsetAsync(zCnts, 0, 8, stream);
    hipMemsetAsync(hW1b + (size_t)N * 128, 0, 256, stream);   // zero pad row
    fill_dummy_kernel<<<(cap + 16 + 255) / 256, 256, 0, stream>>>(eData, cap + 16, N, NGT);
    histrank_kernel<<<(E + 255) / 256, 256, 0, stream>>>(dst, cnt, rank, E);
    scan1p_kernel<<<nb, 256, 0, stream>>>(cnt, offP, N, bSums);
    scan2_kernel<<<1, 256, 0, stream>>>(bSums, nb);
    scan3_kernel<<<nb, 256, 0, stream>>>(offP, N, bSums);
    scatter_kernel<<<(E + 255) / 256, 256, 0, stream>>>(src, dst, wE, gate_type,
                                                        offP, rank, eData, E);
    ginfo_kernel<<<(nGroups + 255) / 256, 256, 0, stream>>>(eData, cnt, offP, gInfo,
                                                            nGroups, N, gpw);
    nodelists_kernel<<<(N + 255) / 256, 256, 0, stream>>>(cnt, offP, N, gpw,
                                                          zCnts, zList, zCnts + 1, cList);
    prep_all_kernel<<<(prepTot + 255) / 256, 256, 0, stream>>>(emb, W1_0, b1_0, b1_1, b1_2,
                                                               W1_1, W1_2, W2_0, W2_1, W2_2,
                                                               eW1b, eW2, W1T1, W1T2,
                                                               W2T0, W2T1, W2T2,
                                                               Wwh0, Wwh1, Wwh2, NGT);

    if (h16) {
        hipMemsetAsync(readout, 0, (size_t)(out_size - N * 128) * 4, stream);
        zero_rows_kernel<<<64, 256, 0, stream>>>(zList, zCnts, hN16);      // deg-0, once
        zero_rows_kernel<<<64, 256, 0, stream>>>(cList, zCnts + 1, hN16);  // cross, L0
        // layer 0
        edgeW_kernel<true, true><<<EB, 256, 0, stream>>>(eW1b, Wwh0, eData, gInfo, hN, gpw, nGroups);
        node_kernel<true, true, false><<<NB, 512, 0, stream>>>(nullptr, hN, W2T0, eW2, gate_type, n2g,
                                                               hBuf, nullptr, readout, N, tpwN, nTiles, 0);
        // layer 1
        hw1_kernel<<<HB, 512, 0, stream>>>(hBuf, W1T1, b1_1, hW1b, N, tpwH, nTiles);
        zero_rows_kernel<<<64, 256, 0, stream>>>(cList, zCnts + 1, hN16);  // cross, L1
        edgeW_kernel<false, true><<<EB, 256, 0, stream>>>(hW1b, Wwh1, eData, gInfo, hN, gpw, nGroups);
        node_kernel<true, false, false><<<NB, 512, 0, stream>>>(hBuf, hN, W2T1, nullptr, nullptr, n2g,
                                                                hBuf, nullptr, readout, N, tpwN, nTiles, 128);
        // layer 2
        hw1_kernel<<<HB, 512, 0, stream>>>(hBuf, W1T2, b1_2, hW1b, N, tpwH, nTiles);
        zero_rows_kernel<<<64, 256, 0, stream>>>(cList, zCnts + 1, hN16);  // cross, L2
        edgeW_kernel<false, true><<<EB, 256, 0, stream>>>(hW1b, Wwh2, eData, gInfo, hN, gpw, nGroups);
        node_kernel<true, false, true><<<NB, 512, 0, stream>>>(hBuf, hN, W2T2, nullptr, nullptr, n2g,
                                                               nullptr, (float*)d_out, readout, N, tpwN, nTiles, 256);
    } else {
        hipMemsetAsync(d_out, 0, (size_t)out_size * 4, stream);
        // layer 0
        edgeW_kernel<true, false><<<EB, 256, 0, stream>>>(eW1b, Wwh0, eData, gInfo, hN, gpw, nGroups);
        node_kernel<false, true, false><<<NB, 512, 0, stream>>>(nullptr, hN, W2T0, eW2, gate_type, n2g,
                                                                hBuf, nullptr, readout, N, tpwN, nTiles, 0);
        // layer 1
        hw1_kernel<<<HB, 512, 0, stream>>>(hBuf, W1T1, b1_1, hW1b, N, tpwH, nTiles);
        hipMemsetAsync(d_out, 0, (size_t)N * 128 * 4, stream);
        edgeW_kernel<false, false><<<EB, 256, 0, stream>>>(hW1b, Wwh1, eData, gInfo, hN, gpw, nGroups);
        node_kernel<false, false, false><<<NB, 512, 0, stream>>>(hBuf, hN, W2T1, nullptr, nullptr, n2g,
                                                                 hBuf, nullptr, readout, N, tpwN, nTiles, 128);
        // layer 2
        hw1_kernel<<<HB, 512, 0, stream>>>(hBuf, W1T2, b1_2, hW1b, N, tpwH, nTiles);
        hipMemsetAsync(d_out, 0, (size_t)N * 128 * 4, stream);
        edgeW_kernel<false, false><<<EB, 256, 0, stream>>>(hW1b, Wwh2, eData, gInfo, hN, gpw, nGroups);
        node_kernel<false, false, true><<<NB, 512, 0, stream>>>(hBuf, hN, W2T2, nullptr, nullptr, n2g,
                                                                nullptr, (float*)d_out, readout, N, tpwN, nTiles, 256);
    }
}

// Round 18
// 481.075 us; speedup vs baseline: 1.1422x; 1.0367x over previous
//
#include <hip/hip_runtime.h>
#include <hip/hip_bf16.h>
#include <hip/hip_fp16.h>

typedef _Float16 half8 __attribute__((ext_vector_type(8)));
typedef _Float16 half4 __attribute__((ext_vector_type(4)));
typedef _Float16 h2    __attribute__((ext_vector_type(2)));
typedef float floatx4 __attribute__((ext_vector_type(4)));

__device__ __forceinline__ _Float16 f2h(float f) { return (_Float16)f; }

// eData slot (16B): {src | gt<<24, dst, w01 (2xf16), w2_one (2xf16)}
// dummy slot: {N | NGT<<24, N, 0, 0};  groups are 4 edges (pad-to-4 per dst)

// ---------------------------------------------------------------------------
// hist + per-edge arrival rank (removes the atomic from scatter)
__global__ void histrank_kernel(const int* __restrict__ dst, int* __restrict__ cnt,
                                int* __restrict__ rank, int E)
{
    int e = blockIdx.x * 256 + threadIdx.x;
    if (e < E) rank[e] = atomicAdd(&cnt[dst[e]], 1);
}

// exclusive scan of per-node counts PADDED to multiple of 4 -> offP
__global__ void scan1p_kernel(const int* __restrict__ cnt, int* __restrict__ offP,
                              int n, int* __restrict__ blockSums)
{
    __shared__ int sm[256];
    const int t = threadIdx.x;
    const int base = blockIdx.x * 1024 + t * 4;
    int v[4]; int s = 0;
#pragma unroll
    for (int i = 0; i < 4; ++i) {
        v[i] = (base + i < n) ? ((cnt[base + i] + 3) & ~3) : 0;
        s += v[i];
    }
    sm[t] = s; __syncthreads();
#pragma unroll
    for (int off = 1; off < 256; off <<= 1) {
        int y = (t >= off) ? sm[t - off] : 0;
        __syncthreads();
        if (t >= off) sm[t] += y;
        __syncthreads();
    }
    int excl = sm[t] - s;
    if (t == 255) blockSums[blockIdx.x] = sm[255];
    int run = excl;
#pragma unroll
    for (int i = 0; i < 4; ++i) {
        if (base + i < n) offP[base + i] = run;
        run += v[i];
    }
}

__global__ void scan2_kernel(int* __restrict__ blockSums, int nb)
{
    __shared__ int sm[256];
    const int t = threadIdx.x;
    int s = (t < nb) ? blockSums[t] : 0;
    sm[t] = s; __syncthreads();
#pragma unroll
    for (int off = 1; off < 256; off <<= 1) {
        int y = (t >= off) ? sm[t - off] : 0;
        __syncthreads();
        if (t >= off) sm[t] += y;
        __syncthreads();
    }
    if (t < nb) blockSums[t] = sm[t] - s;
}

__global__ void scan3_kernel(int* __restrict__ offP, int n, const int* __restrict__ blockSums)
{
    const int base = blockIdx.x * 1024 + threadIdx.x * 4;
    const int add = blockSums[blockIdx.x];
#pragma unroll
    for (int i = 0; i < 4; ++i)
        if (base + i < n) offP[base + i] += add;
}

// single 16B store per edge into the sorted slot (rank precomputed, no atomic)
__global__ void scatter_kernel(const int* __restrict__ src, const int* __restrict__ dst,
                               const float* __restrict__ w, const int* __restrict__ gt,
                               const int* __restrict__ offP, const int* __restrict__ rank,
                               int4* __restrict__ eData, int E)
{
    int e = blockIdx.x * 256 + threadIdx.x;
    if (e >= E) return;
    int d = dst[e];
    int p = offP[d] + rank[e];
    int s = src[e];
    h2 w01 = { f2h(w[(size_t)e * 3 + 0]), f2h(w[(size_t)e * 3 + 1]) };
    h2 w2o = { f2h(w[(size_t)e * 3 + 2]), (_Float16)1.0f };
    int4 v = { s | (gt[s] << 24), d,
               __builtin_bit_cast(int, w01), __builtin_bit_cast(int, w2o) };
    eData[p] = v;
}

// per-dst metadata: writes gInfo for own groups, pad eData slots, deg0/cross
// lists, and (d==N-1) the padded slot total.
__global__ void meta_kernel(const int* __restrict__ cnt, const int* __restrict__ offP,
                            int N, int gpw, int NGT,
                            unsigned* __restrict__ gInfo, int4* __restrict__ eData,
                            int* __restrict__ zCnt, int* __restrict__ zList,
                            int* __restrict__ cCnt, int* __restrict__ cList,
                            int* __restrict__ totPtr)
{
    int d = blockIdx.x * 256 + threadIdx.x;
    if (d >= N) return;
    const int c = cnt[d];
    const int o = offP[d];
    if (c == 0) {
        zList[atomicAdd(zCnt, 1)] = d;
        if (d == N - 1) *totPtr = o;
        return;
    }
    const int cntP = (c + 3) & ~3;
    const int gA = o >> 2;
    const int nG = cntP >> 2;
    const bool cross = (gA / gpw) != ((gA + nG - 1) / gpw);
    const unsigned gi = (unsigned)d | (cross ? 0x80000000u : 0u);
    for (int g = gA; g < gA + nG; ++g) gInfo[g] = gi;
    const int4 dummy = {N | (NGT << 24), N, 0, 0};
    for (int s = o + c; s < o + cntP; ++s) eData[s] = dummy;
    if (cross) cList[atomicAdd(cCnt, 1)] = d;
    if (d == N - 1) *totPtr = o + cntP;
}

// mark the dummy gInfo tail (eData tail is never read for dummy groups)
__global__ void gtail_kernel(const int* __restrict__ totPtr,
                             unsigned* __restrict__ gInfo, int nGroupsPad)
{
    const int g0 = (*totPtr) >> 2;
    for (int g = g0 + blockIdx.x * 256 + threadIdx.x; g < nGroupsPad; g += gridDim.x * 256)
        gInfo[g] = 0xFFFFFFFFu;
}

__global__ void zero_rows_kernel(const int* __restrict__ list, const int* __restrict__ cntPtr,
                                 _Float16* __restrict__ hN)
{
    const int n = *cntPtr * 16;              // 16 x 16B chunks per 256B row
    for (int i = blockIdx.x * 256 + threadIdx.x; i < n; i += gridDim.x * 256) {
        const int row = list[i >> 4], c = (i & 15) * 8;
        int4 zz = {0, 0, 0, 0};
        *(int4*)(hN + (size_t)row * 128 + c) = zz;
    }
}

// ---------------------------------------------------------------------------
// ONE kernel for all weight prep
// ---------------------------------------------------------------------------
__global__ void prep_all_kernel(const float* __restrict__ emb,
                                const float* __restrict__ W1_0, const float* __restrict__ b1_0,
                                const float* __restrict__ b1_1, const float* __restrict__ b1_2,
                                const float* __restrict__ W1_1, const float* __restrict__ W1_2,
                                const float* __restrict__ W2_0, const float* __restrict__ W2_1,
                                const float* __restrict__ W2_2,
                                _Float16* __restrict__ eW1b, float* __restrict__ eW2,
                                _Float16* __restrict__ W1T1, _Float16* __restrict__ W1T2,
                                _Float16* __restrict__ W2T0, _Float16* __restrict__ W2T1,
                                _Float16* __restrict__ W2T2,
                                _Float16* __restrict__ Wwh0, _Float16* __restrict__ Wwh1,
                                _Float16* __restrict__ Wwh2, int NGT)
{
    int idx = blockIdx.x * 256 + threadIdx.x;
    const int nE1 = (NGT + 1) * 128;
    if (idx < nE1) {
        int g = idx >> 7, f = idx & 127;
        float s = 0.0f;
        if (g < NGT) {
            s = b1_0[f];
            for (int k = 0; k < 64; ++k) s += emb[g * 64 + k] * W1_0[(size_t)k * 128 + f];
        }
        eW1b[idx] = f2h(s);
        return;
    }
    idx -= nE1;
    const int nE2 = NGT * 128;
    if (idx < nE2) {
        int g = idx >> 7, f = idx & 127;
        float s = 0.0f;
        for (int k = 0; k < 64; ++k) s += emb[g * 64 + k] * W2_0[(size_t)k * 128 + f];
        eW2[idx] = s;
        return;
    }
    idx -= nE2;
    if (idx < 16384) { int f = idx >> 7, k = idx & 127;
        W1T1[idx] = f2h(W1_1[(size_t)k * 128 + f]); return; }
    idx -= 16384;
    if (idx < 16384) { int f = idx >> 7, k = idx & 127;
        W1T2[idx] = f2h(W1_2[(size_t)k * 128 + f]); return; }
    idx -= 16384;
    if (idx < 16384) { int f = idx >> 7, k = idx & 127;
        W2T0[idx] = f2h(W2_0[(size_t)(64 + k) * 128 + f]); return; }
    idx -= 16384;
    if (idx < 32768) { int f = idx >> 8, k = idx & 255;
        W2T1[idx] = f2h(W2_1[(size_t)k * 128 + f]); return; }
    idx -= 32768;
    if (idx < 32768) { int f = idx >> 8, k = idx & 255;
        W2T2[idx] = f2h(W2_2[(size_t)k * 128 + f]); return; }
    idx -= 32768;
    if (idx < 384) { Wwh0[idx] = f2h(W1_0[(size_t)(64 + idx / 128) * 128 + (idx & 127)]); return; }
    idx -= 384;
    if (idx < 384) { Wwh1[idx] = f2h(W1_1[(size_t)(128 + idx / 128) * 128 + (idx & 127)]); return; }
    idx -= 384;
    if (idx < 384) { Wwh2[idx] = f2h(W1_2[(size_t)(128 + idx / 128) * 128 + (idx & 127)]); return; }
}

// ---------------------------------------------------------------------------
// hW1b = h @ W1[:128] + b1  (dense, per-node; feeds the edge kernel)
// ---------------------------------------------------------------------------
__global__ void __launch_bounds__(512, 2)
hw1_kernel(const _Float16* __restrict__ hA,   // [N,128]
           const _Float16* __restrict__ WT,   // [128 outcol, 128 k] f16
           const float* __restrict__ b1,
           _Float16* __restrict__ out,        // [(N+1),128]
           int N, int tilesPerWave, int nTiles)
{
    __shared__ __align__(16) _Float16 lds[128 * 128];
    const int tid = threadIdx.x;
    for (int s = tid; s < 128 * 16; s += 512) {
        const int row = s / 16, seg = s % 16;
        half8 v = *(const half8*)(WT + (size_t)row * 128 + seg * 8);
        *(half8*)(&lds[row * 128 + ((seg ^ (row & 7)) * 8)]) = v;
    }
    __syncthreads();

    const int lane = tid & 63;
    const int wv   = tid >> 6;
    const int lRow = lane & 15;
    const int lGrp = lane >> 4;

    float b1v[8];
#pragma unroll
    for (int jt = 0; jt < 8; ++jt) b1v[jt] = b1[jt * 16 + lRow];

    const int wave = blockIdx.x * 8 + wv;
    const int t0 = wave * tilesPerWave;
    const int t1 = min(t0 + tilesPerWave, nTiles);

    for (int tile = t0; tile < t1; ++tile) {
        const int i0 = tile * 16;
        const int iA = min(i0 + lRow, N - 1);
        half8 a[4];
#pragma unroll
        for (int kc = 0; kc < 4; ++kc)
            a[kc] = *(const half8*)(hA + (size_t)iA * 128 + kc * 32 + lGrp * 8);

        floatx4 acc[8] = {};
#pragma unroll
        for (int jt = 0; jt < 8; ++jt) {
            const int row = jt * 16 + lRow;
            const int sw = row & 7;
#pragma unroll
            for (int kc = 0; kc < 4; ++kc) {
                half8 b = *(const half8*)(&lds[row * 128 + (((kc * 4 + lGrp) ^ sw) * 8)]);
                acc[jt] = __builtin_amdgcn_mfma_f32_16x16x32_f16(a[kc], b, acc[jt], 0, 0, 0);
            }
        }
#pragma unroll
        for (int r = 0; r < 4; ++r) {
            const int i = i0 + lGrp * 4 + r;
            if (i < N) {
#pragma unroll
                for (int jt = 0; jt < 8; ++jt)
                    out[(size_t)i * 128 + jt * 16 + lRow] = f2h(acc[jt][r] + b1v[jt]);
            }
        }
    }
}

// ---------------------------------------------------------------------------
// edge kernel: lane = (edge-slot = lane>>4, 8 cols = (lane&15)*8).
// ---------------------------------------------------------------------------
template<bool L0, bool H16>
__global__ void __launch_bounds__(256, 4)
edgeW_kernel(const _Float16* __restrict__ T,    // embW1b (L0) or hW1b
             const _Float16* __restrict__ Wwh,  // [3][128] f16
             const int4* __restrict__ eData,
             const unsigned* __restrict__ gInfo,
             void* __restrict__ hNv, int groupsPerWave, int nGroups)
{
    const int tid  = threadIdx.x;
    const int lane = tid & 63;
    const int wv   = tid >> 6;
    const int eidx = lane >> 4;          // edge slot 0..3 within group
    const int c8   = (lane & 15) * 8;    // 8 consecutive output cols

    const h2 z = {(_Float16)0.0f, (_Float16)0.0f};
    h2 w0[4], w1[4], w2[4];
#pragma unroll
    for (int j = 0; j < 4; ++j) {
        w0[j] = *(const h2*)(Wwh + 0 * 128 + c8 + 2 * j);
        w1[j] = *(const h2*)(Wwh + 1 * 128 + c8 + 2 * j);
        w2[j] = *(const h2*)(Wwh + 2 * 128 + c8 + 2 * j);
    }

    const int wave = blockIdx.x * 4 + wv;
    const int g0 = wave * groupsPerWave;
    const int g1 = min(g0 + groupsPerWave, nGroups);
    if (g0 >= g1) return;

    int runD = -1; bool runCross = false;
    h2 a0 = z, a1 = z, a2 = z, a3 = z;

    auto flush = [&]() {
        if (runD < 0) return;
        h2 s0 = a0, s1 = a1, s2 = a2, s3 = a3;
#pragma unroll
        for (int m = 16; m <= 32; m <<= 1) {
            int t0_ = __shfl_xor(__builtin_bit_cast(int, s0), m);
            int t1_ = __shfl_xor(__builtin_bit_cast(int, s1), m);
            int t2_ = __shfl_xor(__builtin_bit_cast(int, s2), m);
            int t3_ = __shfl_xor(__builtin_bit_cast(int, s3), m);
            s0 = s0 + __builtin_bit_cast(h2, t0_);
            s1 = s1 + __builtin_bit_cast(h2, t1_);
            s2 = s2 + __builtin_bit_cast(h2, t2_);
            s3 = s3 + __builtin_bit_cast(h2, t3_);
        }
        if (lane < 16) {
            if (H16) {
                if (runCross) {
                    __half2* p = (__half2*)((__half*)hNv + (size_t)runD * 128 + c8);
                    unsafeAtomicAdd(p + 0, __builtin_bit_cast(__half2, s0));
                    unsafeAtomicAdd(p + 1, __builtin_bit_cast(__half2, s1));
                    unsafeAtomicAdd(p + 2, __builtin_bit_cast(__half2, s2));
                    unsafeAtomicAdd(p + 3, __builtin_bit_cast(__half2, s3));
                } else {
                    int4 pk = { __builtin_bit_cast(int, s0), __builtin_bit_cast(int, s1),
                                __builtin_bit_cast(int, s2), __builtin_bit_cast(int, s3) };
                    *(int4*)((__half*)hNv + (size_t)runD * 128 + c8) = pk;
                }
            } else {
                float f[8] = {(float)s0[0], (float)s0[1], (float)s1[0], (float)s1[1],
                              (float)s2[0], (float)s2[1], (float)s3[0], (float)s3[1]};
                float* p = (float*)hNv + (size_t)runD * 128 + c8;
                if (runCross) {
#pragma unroll
                    for (int j = 0; j < 8; ++j) unsafeAtomicAdd(p + j, f[j]);
                } else {
                    floatx4 q0 = {f[0], f[1], f[2], f[3]};
                    floatx4 q1 = {f[4], f[5], f[6], f[7]};
                    *(floatx4*)(p) = q0;
                    *(floatx4*)(p + 4) = q1;
                }
            }
        }
    };

    for (int g = g0; g < g1; ++g) {
        const unsigned gi = gInfo[g];
        if (gi == 0xFFFFFFFFu) break;
        const int dG = (int)(gi & 0xFFFFFFu);

        const int4 e = eData[g * 4 + eidx];
        const int r_ = L0 ? (e.x >> 24) : (e.x & 0xFFFFFF);
        const half8 Tv = *(const half8*)(T + (size_t)r_ * 128 + c8);
        const h2 w01 = __builtin_bit_cast(h2, e.z);
        const h2 w2o = __builtin_bit_cast(h2, e.w);

        h2 m0 = h2{Tv[0], Tv[1]} + w01[0] * w0[0] + w01[1] * w1[0] + w2o[0] * w2[0];
        h2 m1 = h2{Tv[2], Tv[3]} + w01[0] * w0[1] + w01[1] * w1[1] + w2o[0] * w2[1];
        h2 m2 = h2{Tv[4], Tv[5]} + w01[0] * w0[2] + w01[1] * w1[2] + w2o[0] * w2[2];
        h2 m3 = h2{Tv[6], Tv[7]} + w01[0] * w0[3] + w01[1] * w1[3] + w2o[0] * w2[3];
        h2 r0 = __builtin_elementwise_max(m0, z);
        h2 r1 = __builtin_elementwise_max(m1, z);
        h2 r2 = __builtin_elementwise_max(m2, z);
        h2 r3 = __builtin_elementwise_max(m3, z);

        if (dG == runD) {
            a0 = a0 + r0; a1 = a1 + r1; a2 = a2 + r2; a3 = a3 + r3;
        } else {
            flush();
            runD = dG; runCross = (gi >> 31) != 0;
            a0 = r0; a1 = r1; a2 = r2; a3 = r3;
        }
    }
    flush();
}

// ---------------------------------------------------------------------------
// node kernel (2-tile batched, 512 threads -> 16 waves/CU)
// ---------------------------------------------------------------------------
template<bool H16, bool L0, bool LAST>
__global__ void __launch_bounds__(512, 2)
node_kernel(const _Float16* __restrict__ hA,    // [N,128] (unused if L0)
            const void* __restrict__ hNv,       // [N,128] f16 or f32
            const _Float16* __restrict__ W2T,   // [128,K2]
            const float* __restrict__ embW2,    // [30,128] (L0 only)
            const int* __restrict__ gt,         // (L0 only)
            const int* __restrict__ n2g,
            _Float16* __restrict__ hOut,        // if !LAST
            float* __restrict__ fOut,           // if LAST
            float* __restrict__ readout,
            int N, int tilesPerWave, int nTiles, int layerOff)
{
    constexpr int K2  = L0 ? 128 : 256;
    constexpr int KCA = L0 ? 0 : 4;
    constexpr int KC  = K2 / 32;
    constexpr int SPR = K2 / 8;
    __shared__ __align__(16) _Float16 lds[128 * K2];

    const int tid = threadIdx.x;
    for (int s = tid; s < 128 * SPR; s += 512) {
        const int row = s / SPR, seg = s % SPR;
        half8 v = *(const half8*)(W2T + (size_t)row * K2 + seg * 8);
        *(half8*)(&lds[row * K2 + ((seg ^ (row & 7)) * 8)]) = v;
    }
    __syncthreads();

    const int lane = tid & 63;
    const int wv   = tid >> 6;
    const int lRow = lane & 15;
    const int lGrp = lane >> 4;
    const int wave = blockIdx.x * 8 + wv;
    const int t0 = wave * tilesPerWave;
    const int t1 = min(t0 + tilesPerWave, nTiles);
    if (t0 >= t1) return;

    int gCur = -1; float racc[8];
#pragma unroll
    for (int jt = 0; jt < 8; ++jt) racc[jt] = 0.0f;

    auto loadA = [&](int i0, half8 (&afrag)[KC]) {
        const int iA = min(i0 + lRow, N - 1);
#pragma unroll
        for (int kc = 0; kc < KCA; ++kc)
            afrag[kc] = *(const half8*)(hA + (size_t)iA * 128 + kc * 32 + lGrp * 8);
        if (H16) {
            const _Float16* hN = (const _Float16*)hNv;
#pragma unroll
            for (int kc = KCA; kc < KC; ++kc)
                afrag[kc] = *(const half8*)(hN + (size_t)iA * 128 + (kc - KCA) * 32 + lGrp * 8);
        } else {
            const float* hN = (const float*)hNv;
#pragma unroll
            for (int kc = KCA; kc < KC; ++kc) {
                const float* p = hN + (size_t)iA * 128 + (kc - KCA) * 32 + lGrp * 8;
                floatx4 f0 = *(const floatx4*)(p);
                floatx4 f1 = *(const floatx4*)(p + 4);
                half8 a;
#pragma unroll
                for (int i = 0; i < 4; ++i) { a[i] = f2h(f0[i]); a[i + 4] = f2h(f1[i]); }
                afrag[kc] = a;
            }
        }
    };

    auto epilogue = [&](int i0, floatx4 (&acc)[8]) {
        if (L0) {
#pragma unroll
            for (int r = 0; r < 4; ++r) {
                const int i = min(i0 + lGrp * 4 + r, N - 1);
                const int g_t = gt[i];
#pragma unroll
                for (int jt = 0; jt < 8; ++jt)
                    acc[jt][r] += embW2[(size_t)g_t * 128 + jt * 16 + lRow];
            }
        }
        float scl[4];
#pragma unroll
        for (int r = 0; r < 4; ++r) {
            float s = 0.f;
#pragma unroll
            for (int jt = 0; jt < 8; ++jt) {
                float v = fmaxf(acc[jt][r], 0.0f);
                s += v * v;
            }
#pragma unroll
            for (int m = 1; m <= 8; m <<= 1) s += __shfl_xor(s, m);
            scl[r] = 1.0f / fmaxf(sqrtf(s), 1e-12f);
        }
#pragma unroll
        for (int r = 0; r < 4; ++r) {
            const int i = i0 + lGrp * 4 + r;
            if (i < N) {
#pragma unroll
                for (int jt = 0; jt < 8; ++jt) {
                    float v = fmaxf(acc[jt][r], 0.0f) * scl[r];
                    if (LAST) fOut[(size_t)i * 128 + jt * 16 + lRow] = v;
                    else      hOut[(size_t)i * 128 + jt * 16 + lRow] = f2h(v);
                }
            }
        }
        const int gFirst = n2g[min(i0, N - 1)];
        const int gLast  = n2g[min(i0 + 15, N - 1)];
        if (gFirst == gLast && i0 + 15 < N) {
            if (gFirst != gCur) {
                if (gCur >= 0 && lane < 16) {
#pragma unroll
                    for (int jt = 0; jt < 8; ++jt)
                        unsafeAtomicAdd(&readout[(size_t)gCur * 384 + layerOff + jt * 16 + lane], racc[jt]);
                }
                gCur = gFirst;
#pragma unroll
                for (int jt = 0; jt < 8; ++jt) racc[jt] = 0.0f;
            }
#pragma unroll
            for (int jt = 0; jt < 8; ++jt) {
                float t = 0.f;
#pragma unroll
                for (int r = 0; r < 4; ++r) t += fmaxf(acc[jt][r], 0.0f) * scl[r];
                t += __shfl_xor(t, 16);
                t += __shfl_xor(t, 32);
                racc[jt] += t;
            }
        } else {
            if (gCur >= 0 && lane < 16) {
#pragma unroll
                for (int jt = 0; jt < 8; ++jt)
                    unsafeAtomicAdd(&readout[(size_t)gCur * 384 + layerOff + jt * 16 + lane], racc[jt]);
            }
            gCur = -1;
#pragma unroll
            for (int jt = 0; jt < 8; ++jt) racc[jt] = 0.0f;
#pragma unroll
            for (int r = 0; r < 4; ++r) {
                const int i = i0 + lGrp * 4 + r;
                if (i < N) {
                    const int g = n2g[i];
#pragma unroll
                    for (int jt = 0; jt < 8; ++jt) {
                        float v = fmaxf(acc[jt][r], 0.0f) * scl[r];
                        unsafeAtomicAdd(&readout[(size_t)g * 384 + layerOff + jt * 16 + lRow], v);
                    }
                }
            }
        }
    };

    for (int tile = t0; tile < t1; tile += 2) {
        const bool has2 = (tile + 1 < t1);
        const int i0a = tile * 16;
        const int i0b = has2 ? (tile + 1) * 16 : i0a;

        half8 afA[KC], afB[KC];
        loadA(i0a, afA);
        loadA(i0b, afB);

        floatx4 accA[8] = {}, accB[8] = {};
#pragma unroll
        for (int jt = 0; jt < 8; ++jt) {
            const int rb = (jt * 16 + lRow) * K2;
            const int sw = (jt * 16 + lRow) & 7;
#pragma unroll
            for (int kc = 0; kc < KC; ++kc) {
                half8 b = *(const half8*)(&lds[rb + (((kc * 4 + lGrp) ^ sw) * 8)]);
                accA[jt] = __builtin_amdgcn_mfma_f32_16x16x32_f16(afA[kc], b, accA[jt], 0, 0, 0);
                accB[jt] = __builtin_amdgcn_mfma_f32_16x16x32_f16(afB[kc], b, accB[jt], 0, 0, 0);
            }
        }
        epilogue(i0a, accA);
        if (has2) epilogue(i0b, accB);
    }
    if (gCur >= 0 && lane < 16) {
#pragma unroll
        for (int jt = 0; jt < 8; ++jt)
            unsafeAtomicAdd(&readout[(size_t)gCur * 384 + layerOff + jt * 16 + lane], racc[jt]);
    }
}

// ---------------------------------------------------------------------------
extern "C" void kernel_launch(void* const* d_in, const int* in_sizes, int n_in,
                              void* d_out, int out_size, void* d_ws, size_t ws_size,
                              hipStream_t stream)
{
    const int*   gate_type = (const int*)d_in[0];
    const int*   src  = (const int*)d_in[1];
    const int*   dst  = (const int*)d_in[2];
    const float* wE   = (const float*)d_in[3];
    const int*   n2g  = (const int*)d_in[4];
    const float* emb  = (const float*)d_in[5];
    const float* W1_0 = (const float*)d_in[6];
    const float* b1_0 = (const float*)d_in[7];
    const float* W2_0 = (const float*)d_in[8];
    const float* W1_1 = (const float*)d_in[9];
    const float* b1_1 = (const float*)d_in[10];
    const float* W2_1 = (const float*)d_in[11];
    const float* W1_2 = (const float*)d_in[12];
    const float* b1_2 = (const float*)d_in[13];
    const float* W2_2 = (const float*)d_in[14];

    const int N = in_sizes[0];
    const int E = in_sizes[1];
    const int NGT = in_sizes[5] / 64;
    const int cap = (E + 3 * N + 15) & ~15;

    char* ws = (char*)d_ws;
    size_t off = 0;
    auto alloc = [&](size_t bytes) { void* p = ws + off; off = (off + bytes + 255) & ~255ULL; return p; };
    _Float16* hBuf  = (_Float16*)alloc((size_t)N * 128 * 2);
    int4*     eData = (int4*)alloc(((size_t)cap + 16) * 16);
    unsigned* gInfo = (unsigned*)alloc(((size_t)cap / 4 + 4) * 4);
    int*      cnt   = (int*)alloc((size_t)N * 4);
    int*      offP  = (int*)alloc((size_t)N * 4);
    int*      rank  = (int*)alloc((size_t)E * 4);
    int*      bSums = (int*)alloc(256 * 4);
    int*      zCnts = (int*)alloc(256);           // [0]=deg0, [1]=cross, [2]=slotTotal
    int*      zList = (int*)alloc((size_t)N * 4);
    int*      cList = (int*)alloc((size_t)N * 4);
    _Float16* W1T1  = (_Float16*)alloc((size_t)128 * 128 * 2);
    _Float16* W1T2  = (_Float16*)alloc((size_t)128 * 128 * 2);
    _Float16* W2T0  = (_Float16*)alloc((size_t)128 * 128 * 2);
    _Float16* W2T1  = (_Float16*)alloc((size_t)128 * 256 * 2);
    _Float16* W2T2  = (_Float16*)alloc((size_t)128 * 256 * 2);
    _Float16* Wwh0  = (_Float16*)alloc((size_t)3 * 128 * 2);
    _Float16* Wwh1  = (_Float16*)alloc((size_t)3 * 128 * 2);
    _Float16* Wwh2  = (_Float16*)alloc((size_t)3 * 128 * 2);
    _Float16* eW1b  = (_Float16*)alloc((size_t)(NGT + 1) * 128 * 2);
    float*    eW2   = (float*)alloc((size_t)NGT * 128 * 4);
    _Float16* hW1b  = (_Float16*)alloc(((size_t)N + 1) * 128 * 2);
    size_t hn16_off = off;
    const bool h16 = (ws_size >= hn16_off + (size_t)N * 128 * 2 + 256);
    _Float16* hN16 = (_Float16*)alloc((size_t)N * 128 * 2);

    float* readout = (float*)d_out + (size_t)N * 128;  // [G,384]
    void*  hN      = h16 ? (void*)hN16 : (void*)d_out;

    const int nGroups = cap / 4;
    const int nTiles  = (N + 15) / 16;
    const int EB = 2048;                                 // edgeW blocks (4 waves)
    const int gpw = (nGroups + EB * 4 - 1) / (EB * 4);
    const int NB = 256;                                  // node blocks (8 waves)
    const int tpwN = (nTiles + NB * 8 - 1) / (NB * 8);
    const int HB = 256;                                  // hw1 blocks (8 waves)
    const int tpwH = (nTiles + HB * 8 - 1) / (HB * 8);
    const int nb = (N + 1023) / 1024;
    const int prepTot = (NGT + 1) * 128 + NGT * 128 + 3 * 16384 + 2 * 32768 + 3 * 384;

    // ---- init + counting sort (padded to 4 per dst, 16B/slot payload) ----
    hipMemsetAsync(cnt, 0, (size_t)N * 4, stream);
    hipMemsetAsync(zCnts, 0, 16, stream);
    hipMemsetAsync(hW1b + (size_t)N * 128, 0, 256, stream);   // zero pad row
    histrank_kernel<<<(E + 255) / 256, 256, 0, stream>>>(dst, cnt, rank, E);
    scan1p_kernel<<<nb, 256, 0, stream>>>(cnt, offP, N, bSums);
    scan2_kernel<<<1, 256, 0, stream>>>(bSums, nb);
    scan3_kernel<<<nb, 256, 0, stream>>>(offP, N, bSums);
    meta_kernel<<<(N + 255) / 256, 256, 0, stream>>>(cnt, offP, N, gpw, NGT,
                                                     gInfo, eData,
                                                     zCnts, zList, zCnts + 1, cList,
                                                     zCnts + 2);
    gtail_kernel<<<32, 256, 0, stream>>>(zCnts + 2, gInfo, nGroups + 4);
    scatter_kernel<<<(E + 255) / 256, 256, 0, stream>>>(src, dst, wE, gate_type,
                                                        offP, rank, eData, E);
    prep_all_kernel<<<(prepTot + 255) / 256, 256, 0, stream>>>(emb, W1_0, b1_0, b1_1, b1_2,
                                                               W1_1, W1_2, W2_0, W2_1, W2_2,
                                                               eW1b, eW2, W1T1, W1T2,
                                                               W2T0, W2T1, W2T2,
                                                               Wwh0, Wwh1, Wwh2, NGT);

    if (h16) {
        hipMemsetAsync(readout, 0, (size_t)(out_size - N * 128) * 4, stream);
        zero_rows_kernel<<<64, 256, 0, stream>>>(zList, zCnts, hN16);      // deg-0, once
        zero_rows_kernel<<<64, 256, 0, stream>>>(cList, zCnts + 1, hN16);  // cross, L0
        // layer 0
        edgeW_kernel<true, true><<<EB, 256, 0, stream>>>(eW1b, Wwh0, eData, gInfo, hN, gpw, nGroups);
        node_kernel<true, true, false><<<NB, 512, 0, stream>>>(nullptr, hN, W2T0, eW2, gate_type, n2g,
                                                               hBuf, nullptr, readout, N, tpwN, nTiles, 0);
        // layer 1
        hw1_kernel<<<HB, 512, 0, stream>>>(hBuf, W1T1, b1_1, hW1b, N, tpwH, nTiles);
        zero_rows_kernel<<<64, 256, 0, stream>>>(cList, zCnts + 1, hN16);  // cross, L1
        edgeW_kernel<false, true><<<EB, 256, 0, stream>>>(hW1b, Wwh1, eData, gInfo, hN, gpw, nGroups);
        node_kernel<true, false, false><<<NB, 512, 0, stream>>>(hBuf, hN, W2T1, nullptr, nullptr, n2g,
                                                                hBuf, nullptr, readout, N, tpwN, nTiles, 128);
        // layer 2
        hw1_kernel<<<HB, 512, 0, stream>>>(hBuf, W1T2, b1_2, hW1b, N, tpwH, nTiles);
        zero_rows_kernel<<<64, 256, 0, stream>>>(cList, zCnts + 1, hN16);  // cross, L2
        edgeW_kernel<false, true><<<EB, 256, 0, stream>>>(hW1b, Wwh2, eData, gInfo, hN, gpw, nGroups);
        node_kernel<true, false, true><<<NB, 512, 0, stream>>>(hBuf, hN, W2T2, nullptr, nullptr, n2g,
                                                               nullptr, (float*)d_out, readout, N, tpwN, nTiles, 256);
    } else {
        hipMemsetAsync(d_out, 0, (size_t)out_size * 4, stream);
        // layer 0
        edgeW_kernel<true, false><<<EB, 256, 0, stream>>>(eW1b, Wwh0, eData, gInfo, hN, gpw, nGroups);
        node_kernel<false, true, false><<<NB, 512, 0, stream>>>(nullptr, hN, W2T0, eW2, gate_type, n2g,
                                                                hBuf, nullptr, readout, N, tpwN, nTiles, 0);
        // layer 1
        hw1_kernel<<<HB, 512, 0, stream>>>(hBuf, W1T1, b1_1, hW1b, N, tpwH, nTiles);
        hipMemsetAsync(d_out, 0, (size_t)N * 128 * 4, stream);
        edgeW_kernel<false, false><<<EB, 256, 0, stream>>>(hW1b, Wwh1, eData, gInfo, hN, gpw, nGroups);
        node_kernel<false, false, false><<<NB, 512, 0, stream>>>(hBuf, hN, W2T1, nullptr, nullptr, n2g,
                                                                 hBuf, nullptr, readout, N, tpwN, nTiles, 128);
        // layer 2
        hw1_kernel<<<HB, 512, 0, stream>>>(hBuf, W1T2, b1_2, hW1b, N, tpwH, nTiles);
        hipMemsetAsync(d_out, 0, (size_t)N * 128 * 4, stream);
        edgeW_kernel<false, false><<<EB, 256, 0, stream>>>(hW1b, Wwh2, eData, gInfo, hN, gpw, nGroups);
        node_kernel<false, false, true><<<NB, 512, 0, stream>>>(hBuf, hN, W2T2, nullptr, nullptr, n2g,
                                                                nullptr, (float*)d_out, readout, N, tpwN, nTiles, 256);
    }
}